// Round 1
// baseline (2417.854 us; speedup 1.0000x reference)
//
#include <hip/hip_runtime.h>

#define BS 256
#define INF_I 0x3fffffff
#define MAXIT 10

// ctrl layout (int indices; ctrl base is 256B aligned)
#define C_DONE  0
#define C_CNT   1
#define C_NEW   2
#define C_HC    3
#define C_KEY   4   // unsigned long long at ints [4],[5]
#define C_BLK   6
#define C_HSTAR 7
#define C_R     8
#define C_LOSS  12  // float
#define C_SUM   16  // float[64]
#define C_V1    80  // float[64]
#define C_V2    144 // float[64]

__device__ inline float softplusf(float x){
  return fmaxf(x, 0.f) + log1pf(expf(-fabsf(x)));
}

__global__ void k_zero_i(int* p, int n){
  int i = blockIdx.x*BS + threadIdx.x, st = gridDim.x*BS;
  for(; i<n; i+=st) p[i]=0;
}

__global__ void k_hist_dst(const int* __restrict__ dst, int E, int* __restrict__ cnt){
  int i = blockIdx.x*BS + threadIdx.x, st = gridDim.x*BS;
  for(; i<E; i+=st) atomicAdd(&cnt[dst[i]], 1);
}

__global__ void k_blocksum(const int* __restrict__ a, int n, int* __restrict__ part){
  __shared__ int s[BS];
  int t=threadIdx.x, i=blockIdx.x*BS+t;
  s[t] = (i<n)? a[i] : 0;
  __syncthreads();
  for(int o=BS/2;o>0;o>>=1){ if(t<o) s[t]+=s[t+o]; __syncthreads(); }
  if(t==0) part[blockIdx.x]=s[0];
}

__global__ void k_scan_serial(int* part, int nb){
  if(blockIdx.x||threadIdx.x) return;
  int acc=0;
  for(int i=0;i<nb;i++){ int v=part[i]; part[i]=acc; acc+=v; }
  part[nb]=acc;
}

__global__ void k_rowptr(const int* __restrict__ cnt, const int* __restrict__ part, int n, int nb,
                         int* __restrict__ rowptr, int* __restrict__ cursor){
  __shared__ int s[BS];
  int b=blockIdx.x, t=threadIdx.x, i=b*BS+t;
  int v=(i<n)?cnt[i]:0;
  s[t]=v; __syncthreads();
  for(int o=1;o<BS;o<<=1){
    int x=(t>=o)? s[t-o]:0;
    __syncthreads();
    if(t>=o) s[t]+=x;
    __syncthreads();
  }
  int excl = s[t]-v+part[b];
  if(i<n){ rowptr[i]=excl; cursor[i]=excl; }
  if(b==0&&t==0) rowptr[n]=part[nb];
}

__global__ void k_scatter(const int* __restrict__ src, const int* __restrict__ dst, int E,
                          int* __restrict__ cursor, int* __restrict__ col){
  int i=blockIdx.x*BS+threadIdx.x, st=gridDim.x*BS;
  for(;i<E;i+=st){
    int p=atomicAdd(&cursor[dst[i]],1);
    col[p]=src[i];
  }
}

// FW = feat @ W_enc   (N x 64) * (64 x 64)
__global__ void k_fw(const float* __restrict__ feat, const float* __restrict__ W,
                     float* __restrict__ FW, int N){
  __shared__ float sW[64*64];
  __shared__ float sf[4][64];
  int t=threadIdx.x;
  for(int i=t;i<64*64;i+=BS) sW[i]=W[i];
  __syncthreads();
  int j=t&63, r=t>>6;
  int ngroups=(N+3)>>2;
  for(int g=blockIdx.x; g<ngroups; g+=gridDim.x){
    int v0=g*4;
    int vr=v0+r;
    sf[r][j] = (vr<N)? feat[vr*64+j] : 0.f;
    __syncthreads();
    if(vr<N){
      float acc=0.f;
      #pragma unroll
      for(int d=0;d<64;d++) acc += sf[r][d]*sW[d*64+j];
      FW[vr*64+j]=acc;
    }
    __syncthreads();
  }
}

// pos/neg GCN: wave per node, lane = feature dim
__global__ void k_posneg(const int* __restrict__ rowptr, const int* __restrict__ col,
                         const float* __restrict__ FW, const int* __restrict__ perm_neg,
                         float* __restrict__ pos, float* __restrict__ neg, int N){
  int t=threadIdx.x, lane=t&63;
  int wid=(blockIdx.x*BS+t)>>6, nw=(gridDim.x*BS)>>6;
  for(int v=wid; v<N; v+=nw){
    int b=rowptr[v], e=rowptr[v+1];
    float ap=0.f, an=0.f;
    for(int i=b;i<e;i++){
      int s=col[i];
      ap += FW[s*64+lane];
      an += FW[perm_neg[s]*64+lane];
    }
    float inv = 1.f/(float)max(e-b,1);
    pos[v*64+lane]=fmaxf(ap*inv,0.f);
    neg[v*64+lane]=fmaxf(an*inv,0.f);
  }
}

__global__ void k_bfs_init(int* __restrict__ hop, int* __restrict__ m, int N,
                           const int* __restrict__ perm, int* __restrict__ ctrl,
                           int* __restrict__ hist){
  int i=blockIdx.x*BS+threadIdx.x, st=gridDim.x*BS;
  int root=perm[0];
  for(int v=i;v<N;v+=st){ hop[v]=(v==root)?0:N; m[v]=INF_I; }
  if(blockIdx.x==0){
    if(threadIdx.x<64){ hist[threadIdx.x]=0; ((float*)ctrl)[C_SUM+threadIdx.x]=0.f; }
    if(threadIdx.x==0){
      ctrl[C_DONE]=0; ctrl[C_CNT]=1; ctrl[C_NEW]=0; ctrl[C_HC]=0; ctrl[C_BLK]=0;
      *(unsigned long long*)&ctrl[C_KEY]=0xFFFFFFFFFFFFFFFFULL;
      ((float*)ctrl)[C_LOSS]=0.f;
    }
  }
}

__global__ void k_relax(const int* __restrict__ src, const int* __restrict__ dst, int E,
                        const int* __restrict__ hop, int* __restrict__ m,
                        const int* __restrict__ ctrl){
  if(ctrl[C_DONE]) return;
  int i=blockIdx.x*BS+threadIdx.x, st=gridDim.x*BS;
  for(int e=i;e<E;e+=st){
    int s=src[e], d=dst[e];
    int h=hop[s] + (s!=d);
    atomicMin(&m[d], h);
  }
}

__global__ void k_update(int* __restrict__ hop, int* __restrict__ m,
                         const int* __restrict__ perm, int N, int* __restrict__ ctrl, int target){
  if(ctrl[C_DONE]) return;
  __shared__ int scnt[BS];
  __shared__ unsigned long long skey[BS];
  int t=threadIdx.x, v=blockIdx.x*BS+t;
  int c=0; unsigned long long key=0xFFFFFFFFFFFFFFFFULL;
  if(v<N){
    int h=min(m[v],hop[v]); hop[v]=h; m[v]=INF_I;
    if(h<N) c=1;
    else key=((unsigned long long)(unsigned)perm[v]<<32)|(unsigned)v;
  }
  __threadfence();  // make this thread's hop/m stores device-visible before the counter
  scnt[t]=c; skey[t]=key;
  __syncthreads();
  for(int o=BS/2;o>0;o>>=1){
    if(t<o){ scnt[t]+=scnt[t+o]; if(skey[t+o]<skey[t]) skey[t]=skey[t+o]; }
    __syncthreads();
  }
  if(t==0){
    atomicAdd(&ctrl[C_NEW], scnt[0]);
    atomicMin((unsigned long long*)&ctrl[C_KEY], skey[0]);
    __threadfence();
    if(atomicAdd(&ctrl[C_BLK],1)==(int)gridDim.x-1){
      __threadfence();
      int newcnt = atomicAdd(&ctrl[C_NEW],0);
      unsigned long long k = atomicAdd((unsigned long long*)&ctrl[C_KEY],0ull);
      int hc = ctrl[C_HC]+1; ctrl[C_HC]=hc;
      int stuck = (newcnt==ctrl[C_CNT]);
      if(stuck && k!=0xFFFFFFFFFFFFFFFFULL){
        int idx=(int)(k & 0xFFFFFFFFULL);
        hop[idx]=hc; newcnt++;
      }
      ctrl[C_CNT]=newcnt;
      atomicExch(&ctrl[C_NEW],0);
      atomicExch((unsigned long long*)&ctrl[C_KEY],0xFFFFFFFFFFFFFFFFULL);
      atomicExch(&ctrl[C_BLK],0);
      if(newcnt>target) ctrl[C_DONE]=1;
      __threadfence();
    }
  }
}

__global__ void k_hop_hist(const int* __restrict__ hop, int N, int* __restrict__ hist){
  __shared__ int lh[64];
  int t=threadIdx.x;
  if(t<64) lh[t]=0;
  __syncthreads();
  int i=blockIdx.x*BS+t, st=gridDim.x*BS;
  for(int v=i;v<N;v+=st) atomicAdd(&lh[min(hop[v],63)],1);
  __syncthreads();
  if(t<64) atomicAdd(&hist[t], lh[t]);
}

__global__ void k_cutoff(const int* __restrict__ hist, int* __restrict__ ctrl, int target){
  if(blockIdx.x||threadIdx.x) return;
  int c=0, hstar=63, r=0;
  for(int h=0;h<64;h++){
    int x=hist[h];
    if(c+x>target){ hstar=h; r=target-c; break; }
    c+=x;
  }
  ctrl[C_HSTAR]=hstar; ctrl[C_R]=r;
}

__global__ void k_flag(const int* __restrict__ hop, const int* __restrict__ perm,
                       int* __restrict__ flag, int N, const int* __restrict__ ctrl){
  int hstar=ctrl[C_HSTAR];
  int i=blockIdx.x*BS+threadIdx.x, st=gridDim.x*BS;
  for(int v=i;v<N;v+=st)
    if(min(hop[v],63)==hstar) flag[perm[v]]=1;
}

__global__ void k_keep(const int* __restrict__ hop, const int* __restrict__ perm,
                       const int* __restrict__ flag, const int* __restrict__ part,
                       int* __restrict__ keep, int N, const int* __restrict__ ctrl){
  int hstar=ctrl[C_HSTAR], r=ctrl[C_R];
  int i=blockIdx.x*BS+threadIdx.x, st=gridDim.x*BS;
  for(int v=i;v<N;v+=st){
    int h=min(hop[v],63), kp=0;
    if(h<hstar) kp=1;
    else if(h==hstar){
      int p=perm[v];
      int cum=part[p>>8];
      for(int q=(p>>8)<<8; q<=p; q++) cum+=flag[q];  // inclusive rank among level-h* perms
      kp = (cum<=r);
    }
    keep[v]=kp;
  }
}

// subgraph GCN + summary partial reduction (h never materialized)
__global__ void k_subagg(const int* __restrict__ rowptr, const int* __restrict__ col,
                         const float* __restrict__ FW, const int* __restrict__ keep,
                         float* __restrict__ subpart, int N){
  __shared__ float ssum[4][64];
  int t=threadIdx.x, lane=t&63, w=t>>6;
  int wid=(blockIdx.x*BS+t)>>6, nw=(gridDim.x*BS)>>6;
  float acc=0.f;
  for(int v=wid; v<N; v+=nw){
    if(!keep[v]) continue;
    int b=rowptr[v], e=rowptr[v+1];
    float a=0.f; int cnt=0;
    for(int i=b;i<e;i++){
      int s=col[i];
      if(keep[s]){ a+=FW[s*64+lane]; cnt++; }
    }
    acc += fmaxf(a/(float)max(cnt,1), 0.f);
  }
  ssum[w][lane]=acc;
  __syncthreads();
  if(w==0) subpart[blockIdx.x*64+lane]=ssum[0][lane]+ssum[1][lane]+ssum[2][lane]+ssum[3][lane];
}

__global__ void k_reduce_sub(const float* __restrict__ subpart, int nb, float* __restrict__ cf){
  __shared__ float s[BS];
  int t=threadIdx.x, d=t&63, p=t>>6;
  float a=0.f;
  for(int b=p;b<nb;b+=4) a+=subpart[b*64+d];
  s[t]=a;
  __syncthreads();
  if(t<64) cf[C_SUM+t]=s[t]+s[t+64]+s[t+128]+s[t+192];
}

__global__ void k_sumv(const float* __restrict__ Wd, float* __restrict__ cf, int voff, float invk){
  __shared__ float s[64];
  int t=threadIdx.x;
  if(t<64){
    float x=cf[C_SUM+t]*invk;
    s[t]=1.f/(1.f+expf(-x));
  }
  __syncthreads();
  if(t<64){
    float a=0.f;
    #pragma unroll
    for(int d=0;d<64;d++) a+=Wd[t*64+d]*s[d];
    cf[voff+t]=a;
  }
}

__global__ void k_loss(const float* __restrict__ pos, const float* __restrict__ neg,
                       float* __restrict__ cf, int N){
  int t=threadIdx.x, lane=t&63, w=t>>6;
  int wid=(blockIdx.x*BS+t)>>6, nw=(gridDim.x*BS)>>6;
  float v1=cf[C_V1+lane], v2=cf[C_V2+lane];
  float acc=0.f;
  for(int v=wid; v<N; v+=nw){
    float p=pos[v*64+lane], q=neg[v*64+lane];
    float a1=p*v1, a2=p*v2, b1=q*v1, b2=q*v2;
    for(int o=1;o<64;o<<=1){
      a1+=__shfl_xor(a1,o); a2+=__shfl_xor(a2,o);
      b1+=__shfl_xor(b1,o); b2+=__shfl_xor(b2,o);
    }
    if(lane==0) acc += softplusf(-a1)+softplusf(b1)+softplusf(-a2)+softplusf(b2);
  }
  __shared__ float s[4];
  if(lane==0) s[w]=acc;
  __syncthreads();
  if(t==0) atomicAdd(&cf[C_LOSS], s[0]+s[1]+s[2]+s[3]);
}

__global__ void k_final(const float* __restrict__ cf, float* __restrict__ out, int N){
  if(blockIdx.x||threadIdx.x) return;
  out[0]=cf[C_LOSS]/(float)N;
}

extern "C" void kernel_launch(void* const* d_in, const int* in_sizes, int n_in,
                              void* d_out, int out_size, void* d_ws, size_t ws_size,
                              hipStream_t stream) {
  const float* feat    = (const float*)d_in[0];
  const float* Wenc    = (const float*)d_in[1];
  const float* Wdisc   = (const float*)d_in[2];
  const int*   src     = (const int*)d_in[3];
  const int*   dst     = (const int*)d_in[4];
  const int*   permneg = (const int*)d_in[5];
  const int*   perm1   = (const int*)d_in[6];
  const int*   perm2   = (const int*)d_in[7];
  float* out = (float*)d_out;

  int N = in_sizes[5];
  int E = in_sizes[3];
  int target = (int)((double)N*0.8);
  int NB = (N+BS-1)/BS;
  int gE = (E+BS-1)/BS;
  const int SUBB = 2048;

  // workspace carve (256B-aligned chunks)
  char* w = (char*)d_ws;
  auto alloc = [&](size_t bytes)->void*{
    void* p = (void*)w;
    w += (bytes + 255) & ~(size_t)255;
    return p;
  };
  int*   ctrl    = (int*)  alloc(4096);
  int*   cnt     = (int*)  alloc((size_t)N*4);
  int*   rowptr  = (int*)  alloc((size_t)(N+1)*4);
  int*   cursor  = (int*)  alloc((size_t)N*4);
  int*   col     = (int*)  alloc((size_t)E*4);
  int*   hop     = (int*)  alloc((size_t)N*4);
  int*   m       = (int*)  alloc((size_t)N*4);
  int*   keep    = (int*)  alloc((size_t)N*4);
  int*   flag    = (int*)  alloc((size_t)N*4);
  int*   part    = (int*)  alloc((size_t)(NB+2)*4);
  int*   hist    = (int*)  alloc(64*4);
  float* FW      = (float*)alloc((size_t)N*64*4);
  float* pos     = (float*)alloc((size_t)N*64*4);
  float* neg     = (float*)alloc((size_t)N*64*4);
  float* subpart = (float*)alloc((size_t)SUBB*64*4);
  float* cf = (float*)ctrl;

  // --- build CSR (by dst) ---
  k_zero_i   <<<NB, BS, 0, stream>>>(cnt, N);
  k_hist_dst <<<gE, BS, 0, stream>>>(dst, E, cnt);
  k_blocksum <<<NB, BS, 0, stream>>>(cnt, N, part);
  k_scan_serial<<<1, 1, 0, stream>>>(part, NB);
  k_rowptr   <<<NB, BS, 0, stream>>>(cnt, part, N, NB, rowptr, cursor);
  k_scatter  <<<gE, BS, 0, stream>>>(src, dst, E, cursor, col);

  // --- FW = feat @ W_enc ---
  int gFW = (N+3)/4; if(gFW>2048) gFW=2048;
  k_fw<<<gFW, BS, 0, stream>>>(feat, Wenc, FW, N);

  // --- pos / neg GCN ---
  k_posneg<<<(N+3)/4, BS, 0, stream>>>(rowptr, col, FW, permneg, pos, neg, N);

  const int* perms[2] = {perm1, perm2};
  const int voffs[2]  = {C_V1, C_V2};
  for(int pi=0; pi<2; pi++){
    const int* perm = perms[pi];
    k_bfs_init<<<NB, BS, 0, stream>>>(hop, m, N, perm, ctrl, hist);
    for(int it=0; it<MAXIT; it++){
      k_relax <<<gE, BS, 0, stream>>>(src, dst, E, hop, m, ctrl);
      k_update<<<NB, BS, 0, stream>>>(hop, m, perm, N, ctrl, target);
    }
    k_hop_hist<<<1024, BS, 0, stream>>>(hop, N, hist);
    k_cutoff  <<<1, 1, 0, stream>>>(hist, ctrl, target);
    k_zero_i  <<<NB, BS, 0, stream>>>(flag, N);
    k_flag    <<<NB, BS, 0, stream>>>(hop, perm, flag, N, ctrl);
    k_blocksum<<<NB, BS, 0, stream>>>(flag, N, part);
    k_scan_serial<<<1, 1, 0, stream>>>(part, NB);
    k_keep    <<<NB, BS, 0, stream>>>(hop, perm, flag, part, keep, N, ctrl);
    k_subagg  <<<SUBB, BS, 0, stream>>>(rowptr, col, FW, keep, subpart, N);
    k_reduce_sub<<<1, BS, 0, stream>>>(subpart, SUBB, cf);
    k_sumv    <<<1, 64, 0, stream>>>(Wdisc, cf, voffs[pi], 1.f/(float)target);
  }

  k_loss <<<2048, BS, 0, stream>>>(pos, neg, cf, N);
  k_final<<<1, 1, 0, stream>>>(cf, out, N);
}

// Round 2
// 2130.193 us; speedup vs baseline: 1.1350x; 1.1350x over previous
//
#include <hip/hip_runtime.h>
#include <hip/hip_fp16.h>

#define BS 256
#define MAXIT 10

// ctrl int-index layout (ctrl is 256B-aligned)
#define C_DONE  0
#define C_CNT   1
#define C_BLK   2
#define C_HSTAR 3
#define C_R     4
#define C_KEY   6   // unsigned long long @ ints [6],[7] (byte 24, 8B aligned)
#define C_FS    8   // frontier-size slots [it], it=0..MAXIT  (8..18)
#define C_NEWA  20  // newly-claimed slots [it], it=0..MAXIT-1 (20..29)
#define C_LOSS  32  // float
#define C_SUM   64  // float[64]
#define C_V1    128 // float[64]
#define C_V2    192 // float[64]

__device__ inline float softplusf(float x){
  return fmaxf(x, 0.f) + log1pf(expf(-fabsf(x)));
}

// ---------------- CSR build (both directions in shared passes) ----------------
__global__ void k_zero2(int* a, int* b, int n){
  int i=blockIdx.x*BS+threadIdx.x, st=gridDim.x*BS;
  for(; i<n; i+=st){ a[i]=0; b[i]=0; }
}

__global__ void k_deg2(const int* __restrict__ src, const int* __restrict__ dst, int E,
                       int* __restrict__ cntS, int* __restrict__ cntD){
  int i=blockIdx.x*BS+threadIdx.x, st=gridDim.x*BS;
  for(; i<E; i+=st){ atomicAdd(&cntS[src[i]],1); atomicAdd(&cntD[dst[i]],1); }
}

__global__ void k_blocksum(const int* __restrict__ a, int n, int* __restrict__ part){
  __shared__ int s[BS];
  int t=threadIdx.x, i=blockIdx.x*BS+t;
  s[t] = (i<n)? a[i] : 0;
  __syncthreads();
  for(int o=BS/2;o>0;o>>=1){ if(t<o) s[t]+=s[t+o]; __syncthreads(); }
  if(t==0) part[blockIdx.x]=s[0];
}

__global__ void k_scan_serial(int* part, int nb){
  if(blockIdx.x||threadIdx.x) return;
  int acc=0;
  for(int i=0;i<nb;i++){ int v=part[i]; part[i]=acc; acc+=v; }
  part[nb]=acc;
}

__global__ void k_rowptr(const int* __restrict__ cnt, const int* __restrict__ part, int n, int nb,
                         int* __restrict__ rowptr, int* __restrict__ cursor){
  __shared__ int s[BS];
  int b=blockIdx.x, t=threadIdx.x, i=b*BS+t;
  int v=(i<n)?cnt[i]:0;
  s[t]=v; __syncthreads();
  for(int o=1;o<BS;o<<=1){
    int x=(t>=o)? s[t-o]:0;
    __syncthreads();
    if(t>=o) s[t]+=x;
    __syncthreads();
  }
  int excl = s[t]-v+part[b];
  if(i<n){ rowptr[i]=excl; cursor[i]=excl; }
  if(b==0&&t==0) rowptr[n]=part[nb];
}

__global__ void k_scatter2(const int* __restrict__ src, const int* __restrict__ dst, int E,
                           int* __restrict__ curD, int* __restrict__ colD,
                           int* __restrict__ curS, int* __restrict__ colS){
  int i=blockIdx.x*BS+threadIdx.x, st=gridDim.x*BS;
  for(; i<E; i+=st){
    int s=src[i], d=dst[i];
    colD[atomicAdd(&curD[d],1)] = s;   // in-edges:  col = src
    colS[atomicAdd(&curS[s],1)] = d;   // out-edges: col = dst
  }
}

// ---------------- FW = feat @ W_enc  (fp16 output) ----------------
__global__ void k_fw(const float* __restrict__ feat, const float* __restrict__ W,
                     __half* __restrict__ FW, int N){
  __shared__ float sW[64*64];
  __shared__ float sf[4][64];
  int t=threadIdx.x;
  for(int i=t;i<64*64;i+=BS) sW[i]=W[i];
  __syncthreads();
  int j=t&63, r=t>>6;
  int ngroups=(N+3)>>2;
  for(int g=blockIdx.x; g<ngroups; g+=gridDim.x){
    int vr=g*4+r;
    sf[r][j] = (vr<N)? feat[vr*64+j] : 0.f;
    __syncthreads();
    if(vr<N){
      float acc=0.f;
      #pragma unroll
      for(int d=0;d<64;d++) acc += sf[r][d]*sW[d*64+j];
      FW[vr*64+j]=__float2half(acc);
    }
    __syncthreads();
  }
}

// ---------------- frontier BFS ----------------
__global__ void k_bfs_init(int* __restrict__ hop, int N, const int* __restrict__ perm,
                           int* __restrict__ ctrl, int* __restrict__ hist, int* __restrict__ fr0){
  int i=blockIdx.x*BS+threadIdx.x, st=gridDim.x*BS;
  int root=perm[0];
  for(int v=i;v<N;v+=st) hop[v]=(v==root)?0:N;
  if(blockIdx.x==0){
    if(threadIdx.x<64){ hist[threadIdx.x]=0; ((float*)ctrl)[C_SUM+threadIdx.x]=0.f; }
    if(threadIdx.x==0){
      ctrl[C_DONE]=0; ctrl[C_CNT]=1; ctrl[C_BLK]=0;
      *(unsigned long long*)&ctrl[C_KEY]=~0ull;
      for(int k=0;k<=MAXIT;k++) ctrl[C_FS+k]=0;
      for(int k=0;k<MAXIT;k++)  ctrl[C_NEWA+k]=0;
      ctrl[C_FS+0]=1;
      ((float*)ctrl)[C_LOSS]=0.f;
      fr0[0]=root;
    }
  }
}

__global__ void k_frontier(const int* __restrict__ rowptrS, const int* __restrict__ colS,
                           int* __restrict__ hop, const int* __restrict__ frCur,
                           int* __restrict__ frNext, int* __restrict__ ctrl, int it, int N){
  if(ctrl[C_DONE]) return;
  int fs = ctrl[C_FS+it];
  int lvl = it+1;
  int i=blockIdx.x*BS+threadIdx.x, st=gridDim.x*BS;
  for(int f=i; f<fs; f+=st){
    int s=frCur[f];
    int b=rowptrS[s], e=rowptrS[s+1];
    for(int j=b;j<e;j++){
      int d=colS[j];
      if(d==s) continue;                 // weight-0 edge, no-op
      if(hop[d]==N){
        if(atomicCAS(&hop[d], N, lvl)==N){
          int p=atomicAdd(&ctrl[C_NEWA+it],1);
          frNext[p]=d;
        }
      }
    }
  }
}

__global__ void k_fin(int* __restrict__ hop, const int* __restrict__ perm,
                      int* __restrict__ frNext, int* __restrict__ ctrl,
                      int N, int target, int it){
  if(ctrl[C_DONE]) return;
  int newly = ctrl[C_NEWA+it];           // written only by previous kernel
  if(newly != 0){
    if(blockIdx.x==0 && threadIdx.x==0){
      int c = ctrl[C_CNT] + newly;
      ctrl[C_CNT]=c; ctrl[C_FS+it+1]=newly;
      if(c>target) ctrl[C_DONE]=1;
    }
    return;
  }
  // stuck: seed the unreached node with min perm value (rare path)
  __shared__ unsigned long long sk[BS];
  int t=threadIdx.x;
  unsigned long long key=~0ull;
  for(int v=blockIdx.x*BS+t; v<N; v+=gridDim.x*BS)
    if(hop[v]==N){
      unsigned long long k=((unsigned long long)(unsigned)perm[v]<<32)|(unsigned)v;
      if(k<key) key=k;
    }
  sk[t]=key; __syncthreads();
  for(int o=BS/2;o>0;o>>=1){ if(t<o && sk[t+o]<sk[t]) sk[t]=sk[t+o]; __syncthreads(); }
  if(t==0){
    atomicMin((unsigned long long*)&ctrl[C_KEY], sk[0]);
    __threadfence();
    if(atomicAdd(&ctrl[C_BLK],1)==(int)gridDim.x-1){
      __threadfence();
      unsigned long long k=atomicAdd((unsigned long long*)&ctrl[C_KEY],0ull);
      int c=ctrl[C_CNT], fsz=0;
      if(k!=~0ull){
        int idx=(int)(k&0xffffffffu);
        hop[idx]=it+1;
        frNext[0]=idx;
        fsz=1; c+=1;
      }
      ctrl[C_CNT]=c; ctrl[C_FS+it+1]=fsz;
      *(unsigned long long*)&ctrl[C_KEY]=~0ull;
      ctrl[C_BLK]=0;
      if(c>target) ctrl[C_DONE]=1;
    }
  }
}

// ---------------- keep-mask (exact top-target by (hop, perm)) ----------------
__global__ void k_hop_hist(const int* __restrict__ hop, int N, int* __restrict__ hist){
  __shared__ int lh[64];
  int t=threadIdx.x;
  if(t<64) lh[t]=0;
  __syncthreads();
  int i=blockIdx.x*BS+t, st=gridDim.x*BS;
  for(int v=i;v<N;v+=st) atomicAdd(&lh[min(hop[v],63)],1);
  __syncthreads();
  if(t<64) atomicAdd(&hist[t], lh[t]);
}

__global__ void k_cutoff(const int* __restrict__ hist, int* __restrict__ ctrl, int target){
  if(blockIdx.x||threadIdx.x) return;
  int c=0, hstar=63, r=0;
  for(int h=0;h<64;h++){
    int x=hist[h];
    if(c+x>target){ hstar=h; r=target-c; break; }
    c+=x;
  }
  ctrl[C_HSTAR]=hstar; ctrl[C_R]=r;
}

// perm is a bijection -> every flag slot written exactly once (no pre-zero needed)
__global__ void k_flag(const int* __restrict__ hop, const int* __restrict__ perm,
                       int* __restrict__ flag, int N, const int* __restrict__ ctrl){
  int hstar=ctrl[C_HSTAR];
  int i=blockIdx.x*BS+threadIdx.x, st=gridDim.x*BS;
  for(int v=i;v<N;v+=st)
    flag[perm[v]] = (min(hop[v],63)==hstar) ? 1 : 0;
}

__global__ void k_keep(const int* __restrict__ hop, const int* __restrict__ perm,
                       const int* __restrict__ flag, const int* __restrict__ part,
                       int* __restrict__ keep, int N, const int* __restrict__ ctrl){
  int hstar=ctrl[C_HSTAR], r=ctrl[C_R];
  int i=blockIdx.x*BS+threadIdx.x, st=gridDim.x*BS;
  for(int v=i;v<N;v+=st){
    int h=min(hop[v],63), kp=0;
    if(h<hstar) kp=1;
    else if(h==hstar){
      int p=perm[v];
      int cum=part[p>>8];
      for(int q=(p>>8)<<8; q<=p; q++) cum+=flag[q];
      kp = (cum<=r);
    }
    keep[v]=kp;
  }
}

// ---------------- subgraph GCN + on-the-fly summary ----------------
__global__ void k_subagg(const int* __restrict__ rowptr, const int* __restrict__ col,
                         const __half* __restrict__ FW, const int* __restrict__ keep,
                         float* __restrict__ subpart, int N){
  __shared__ float ssum[4][64];
  int t=threadIdx.x, lane=t&63, w=t>>6;
  int wid=(blockIdx.x*BS+t)>>6, nw=(gridDim.x*BS)>>6;
  float acc=0.f;
  for(int v=wid; v<N; v+=nw){
    if(!keep[v]) continue;
    int b=rowptr[v], e=rowptr[v+1];
    float a=0.f; int cnt=0;
    for(int i=b;i<e;i++){
      int s=col[i];
      if(keep[s]){ a+=__half2float(FW[s*64+lane]); cnt++; }
    }
    acc += fmaxf(a/(float)max(cnt,1), 0.f);
  }
  ssum[w][lane]=acc;
  __syncthreads();
  if(w==0) subpart[blockIdx.x*64+lane]=ssum[0][lane]+ssum[1][lane]+ssum[2][lane]+ssum[3][lane];
}

__global__ void k_reduce_sub(const float* __restrict__ subpart, int nb, float* __restrict__ cf){
  __shared__ float s[BS];
  int t=threadIdx.x, d=t&63, p=t>>6;
  float a=0.f;
  for(int b=p;b<nb;b+=4) a+=subpart[b*64+d];
  s[t]=a;
  __syncthreads();
  if(t<64) cf[C_SUM+t]=s[t]+s[t+64]+s[t+128]+s[t+192];
}

__global__ void k_sumv(const float* __restrict__ Wd, float* __restrict__ cf, int voff, float invk){
  __shared__ float s[64];
  int t=threadIdx.x;
  if(t<64){
    float x=cf[C_SUM+t]*invk;
    s[t]=1.f/(1.f+expf(-x));
  }
  __syncthreads();
  if(t<64){
    float a=0.f;
    #pragma unroll
    for(int d=0;d<64;d++) a+=Wd[t*64+d]*s[d];
    cf[voff+t]=a;
  }
}

// ---------------- fused pos/neg GCN + BCE loss (pos/neg never materialized) ----------------
__global__ void k_pnl(const int* __restrict__ rowptr, const int* __restrict__ col,
                      const __half* __restrict__ FW, const int* __restrict__ perm_neg,
                      float* __restrict__ cf, int N){
  int t=threadIdx.x, lane=t&63, w=t>>6;
  float v1=cf[C_V1+lane], v2=cf[C_V2+lane];
  int wid=(blockIdx.x*BS+t)>>6, nw=(gridDim.x*BS)>>6;
  float acc=0.f;
  for(int v=wid; v<N; v+=nw){
    int b=rowptr[v], e=rowptr[v+1];
    float ap=0.f, an=0.f;
    for(int i=b;i<e;i++){
      int s=col[i];
      ap += __half2float(FW[s*64+lane]);
      an += __half2float(FW[perm_neg[s]*64+lane]);
    }
    float inv = 1.f/(float)max(e-b,1);
    float p=fmaxf(ap*inv,0.f), q=fmaxf(an*inv,0.f);
    float a1=p*v1, a2=p*v2, b1=q*v1, b2=q*v2;
    #pragma unroll
    for(int o=1;o<64;o<<=1){
      a1+=__shfl_xor(a1,o); a2+=__shfl_xor(a2,o);
      b1+=__shfl_xor(b1,o); b2+=__shfl_xor(b2,o);
    }
    if(lane==0) acc += softplusf(-a1)+softplusf(b1)+softplusf(-a2)+softplusf(b2);
  }
  __shared__ float s[4];
  if(lane==0) s[w]=acc;
  __syncthreads();
  if(t==0) atomicAdd(&cf[C_LOSS], s[0]+s[1]+s[2]+s[3]);
}

__global__ void k_final(const float* __restrict__ cf, float* __restrict__ out, int N){
  if(blockIdx.x||threadIdx.x) return;
  out[0]=cf[C_LOSS]/(float)N;
}

extern "C" void kernel_launch(void* const* d_in, const int* in_sizes, int n_in,
                              void* d_out, int out_size, void* d_ws, size_t ws_size,
                              hipStream_t stream) {
  const float* feat    = (const float*)d_in[0];
  const float* Wenc    = (const float*)d_in[1];
  const float* Wdisc   = (const float*)d_in[2];
  const int*   src     = (const int*)d_in[3];
  const int*   dst     = (const int*)d_in[4];
  const int*   permneg = (const int*)d_in[5];
  const int*   perm1   = (const int*)d_in[6];
  const int*   perm2   = (const int*)d_in[7];
  float* out = (float*)d_out;

  int N = in_sizes[5];
  int E = in_sizes[3];
  int target = (int)((double)N*0.8);
  int NB = (N+BS-1)/BS;
  int gE = (E+BS-1)/BS; if(gE>4096) gE=4096;
  const int SUBB = 2048;
  const int FB = 256, FINB = 128;

  // workspace carve (256B-aligned chunks)
  char* w = (char*)d_ws;
  auto alloc = [&](size_t bytes)->void*{
    void* p = (void*)w;
    w += (bytes + 255) & ~(size_t)255;
    return p;
  };
  int*    ctrl    = (int*)   alloc(4096);
  int*    cntD    = (int*)   alloc((size_t)N*4);
  int*    cntS    = (int*)   alloc((size_t)N*4);
  int*    rowptrD = (int*)   alloc((size_t)(N+1)*4);
  int*    rowptrS = (int*)   alloc((size_t)(N+1)*4);
  int*    curD    = (int*)   alloc((size_t)N*4);
  int*    curS    = (int*)   alloc((size_t)N*4);
  int*    colD    = (int*)   alloc((size_t)E*4);
  int*    colS    = (int*)   alloc((size_t)E*4);
  int*    hop     = (int*)   alloc((size_t)N*4);
  int*    keep    = (int*)   alloc((size_t)N*4);
  int*    flag    = (int*)   alloc((size_t)N*4);
  int*    fr0     = (int*)   alloc((size_t)N*4);
  int*    fr1     = (int*)   alloc((size_t)N*4);
  int*    part    = (int*)   alloc((size_t)(NB+2)*4);
  int*    hist    = (int*)   alloc(64*4);
  __half* FW      = (__half*)alloc((size_t)N*64*2);
  float*  subpart = (float*) alloc((size_t)SUBB*64*4);
  float*  cf = (float*)ctrl;

  // --- build both CSRs ---
  k_zero2   <<<NB, BS, 0, stream>>>(cntD, cntS, N);
  k_deg2    <<<gE, BS, 0, stream>>>(src, dst, E, cntS, cntD);
  k_blocksum<<<NB, BS, 0, stream>>>(cntD, N, part);
  k_scan_serial<<<1, 1, 0, stream>>>(part, NB);
  k_rowptr  <<<NB, BS, 0, stream>>>(cntD, part, N, NB, rowptrD, curD);
  k_blocksum<<<NB, BS, 0, stream>>>(cntS, N, part);
  k_scan_serial<<<1, 1, 0, stream>>>(part, NB);
  k_rowptr  <<<NB, BS, 0, stream>>>(cntS, part, N, NB, rowptrS, curS);
  k_scatter2<<<gE, BS, 0, stream>>>(src, dst, E, curD, colD, curS, colS);

  // --- FW = feat @ W_enc (fp16) ---
  k_fw<<<2048, BS, 0, stream>>>(feat, Wenc, FW, N);

  const int* perms[2] = {perm1, perm2};
  const int voffs[2]  = {C_V1, C_V2};
  for(int pi=0; pi<2; pi++){
    const int* perm = perms[pi];
    k_bfs_init<<<NB, BS, 0, stream>>>(hop, N, perm, ctrl, hist, fr0);
    for(int it=0; it<MAXIT; it++){
      int* frCur = (it&1)? fr1 : fr0;
      int* frNext= (it&1)? fr0 : fr1;
      k_frontier<<<FB,   BS, 0, stream>>>(rowptrS, colS, hop, frCur, frNext, ctrl, it, N);
      k_fin     <<<FINB, BS, 0, stream>>>(hop, perm, frNext, ctrl, N, target, it);
    }
    k_hop_hist<<<512, BS, 0, stream>>>(hop, N, hist);
    k_cutoff  <<<1, 1, 0, stream>>>(hist, ctrl, target);
    k_flag    <<<NB, BS, 0, stream>>>(hop, perm, flag, N, ctrl);
    k_blocksum<<<NB, BS, 0, stream>>>(flag, N, part);
    k_scan_serial<<<1, 1, 0, stream>>>(part, NB);
    k_keep    <<<NB, BS, 0, stream>>>(hop, perm, flag, part, keep, N, ctrl);
    k_subagg  <<<SUBB, BS, 0, stream>>>(rowptrD, colD, FW, keep, subpart, N);
    k_reduce_sub<<<1, BS, 0, stream>>>(subpart, SUBB, cf);
    k_sumv    <<<1, 64, 0, stream>>>(Wdisc, cf, voffs[pi], 1.f/(float)target);
  }

  // --- fused pos/neg GCN + loss ---
  k_pnl  <<<(N+3)/4, BS, 0, stream>>>(rowptrD, colD, FW, permneg, cf, N);
  k_final<<<1, 1, 0, stream>>>(cf, out, N);
}

// Round 3
// 1998.909 us; speedup vs baseline: 1.2096x; 1.0657x over previous
//
#include <hip/hip_runtime.h>
#include <hip/hip_fp8.h>

#define BS 256
#define MAXIT 10

// ctrl int-index layout (ctrl is 256B-aligned, 4096B)
#define C_DONE  0
#define C_CNT   1
#define C_BLK   2
#define C_HSTAR 3
#define C_R     4
#define C_KEY   6   // unsigned long long @ ints [6],[7]
#define C_FS    8   // frontier-size slots [it], 8..18
#define C_NEWA  20  // newly-claimed slots [it], 20..29
#define C_LOSS  32  // float
#define C_SUM1  64  // float[64]
#define C_SUM2  128 // float[64]
#define C_V1    192 // float[64]
#define C_V2    256 // float[64]

typedef __hip_fp8_e4m3 fp8;

__device__ inline float softplusf(float x){
  return fmaxf(x, 0.f) + log1pf(expf(-fabsf(x)));
}

// ---------------- CSR build ----------------
__global__ void k_zero2(int* a, int* b, int n){
  int i=blockIdx.x*BS+threadIdx.x, st=gridDim.x*BS;
  for(; i<n; i+=st){ a[i]=0; b[i]=0; }
}

__global__ void k_zero1(int* a, int n){
  int i=blockIdx.x*BS+threadIdx.x, st=gridDim.x*BS;
  for(; i<n; i+=st) a[i]=0;
}

__global__ void k_deg2(const int* __restrict__ src, const int* __restrict__ dst, int E,
                       int* __restrict__ cntS, int* __restrict__ cntD){
  int i=blockIdx.x*BS+threadIdx.x, st=gridDim.x*BS;
  for(; i<E; i+=st){ atomicAdd(&cntS[src[i]],1); atomicAdd(&cntD[dst[i]],1); }
}

__global__ void k_blocksum(const int* __restrict__ a, int n, int* __restrict__ part){
  __shared__ int s[BS];
  int t=threadIdx.x, i=blockIdx.x*BS+t;
  s[t] = (i<n)? a[i] : 0;
  __syncthreads();
  for(int o=BS/2;o>0;o>>=1){ if(t<o) s[t]+=s[t+o]; __syncthreads(); }
  if(t==0) part[blockIdx.x]=s[0];
}

// single-block parallel exclusive scan (in place), total at a[n]
__global__ void k_scan_block(int* a, int n){
  __shared__ int s[BS];
  __shared__ int carry;
  int t=threadIdx.x;
  if(t==0) carry=0;
  __syncthreads();
  for(int base=0; base<n; base+=BS){
    int i=base+t;
    int v=(i<n)? a[i] : 0;
    s[t]=v; __syncthreads();
    for(int o=1;o<BS;o<<=1){
      int x=(t>=o)? s[t-o]:0;
      __syncthreads();
      if(t>=o) s[t]+=x;
      __syncthreads();
    }
    if(i<n) a[i]=carry+s[t]-v;
    __syncthreads();
    if(t==0) carry+=s[BS-1];
    __syncthreads();
  }
  if(t==0) a[n]=carry;
}

__global__ void k_rowptr(const int* __restrict__ cnt, const int* __restrict__ part, int n, int nb,
                         int* __restrict__ rowptr, int* __restrict__ cursor){
  __shared__ int s[BS];
  int b=blockIdx.x, t=threadIdx.x, i=b*BS+t;
  int v=(i<n)?cnt[i]:0;
  s[t]=v; __syncthreads();
  for(int o=1;o<BS;o<<=1){
    int x=(t>=o)? s[t-o]:0;
    __syncthreads();
    if(t>=o) s[t]+=x;
    __syncthreads();
  }
  int excl = s[t]-v+part[b];
  if(i<n){ rowptr[i]=excl; cursor[i]=excl; }
  if(b==0&&t==0) rowptr[n]=part[nb];
}

__global__ void k_scatter2(const int* __restrict__ src, const int* __restrict__ dst, int E,
                           int* __restrict__ curD, int* __restrict__ colD,
                           int* __restrict__ curS, int* __restrict__ colS){
  int i=blockIdx.x*BS+threadIdx.x, st=gridDim.x*BS;
  for(; i<E; i+=st){
    int s=src[i], d=dst[i];
    colD[atomicAdd(&curD[d],1)] = s;   // in-edges:  col = src
    colS[atomicAdd(&curS[s],1)] = d;   // out-edges: col = dst
  }
}

// ---------------- FW = feat @ W_enc  (fp8 e4m3 output) ----------------
__global__ void k_fw(const float* __restrict__ feat, const float* __restrict__ W,
                     fp8* __restrict__ FW, int N){
  __shared__ float sW[64*64];
  __shared__ float sf[4][64];
  int t=threadIdx.x;
  for(int i=t;i<64*64;i+=BS) sW[i]=W[i];
  __syncthreads();
  int j=t&63, r=t>>6;
  int ngroups=(N+3)>>2;
  for(int g=blockIdx.x; g<ngroups; g+=gridDim.x){
    int vr=g*4+r;
    sf[r][j] = (vr<N)? feat[vr*64+j] : 0.f;
    __syncthreads();
    if(vr<N){
      float acc=0.f;
      #pragma unroll
      for(int d=0;d<64;d++) acc += sf[r][d]*sW[d*64+j];
      FW[vr*64+j]=fp8(acc);
    }
    __syncthreads();
  }
}

// FWn[v] = FW[perm_neg[v]]  (row permute, 16 dwords per 64B row)
__global__ void k_permrows(const unsigned* __restrict__ FW, const int* __restrict__ pn,
                           unsigned* __restrict__ FWn, int N){
  int i=blockIdx.x*BS+threadIdx.x, st=gridDim.x*BS;
  int tot=N*16;
  for(; i<tot; i+=st){
    int v=i>>4, e=i&15;
    FWn[i]=FW[pn[v]*16+e];
  }
}

// ---------------- frontier BFS ----------------
__global__ void k_bfs_init(int* __restrict__ hop, int N, const int* __restrict__ perm,
                           int* __restrict__ ctrl, int* __restrict__ hist, int* __restrict__ fr0){
  int i=blockIdx.x*BS+threadIdx.x, st=gridDim.x*BS;
  int root=perm[0];
  for(int v=i;v<N;v+=st) hop[v]=(v==root)?0:N;
  if(blockIdx.x==0){
    if(threadIdx.x<64) hist[threadIdx.x]=0;
    if(threadIdx.x==0){
      ctrl[C_DONE]=0; ctrl[C_CNT]=1; ctrl[C_BLK]=0;
      *(unsigned long long*)&ctrl[C_KEY]=~0ull;
      for(int k=0;k<=MAXIT;k++) ctrl[C_FS+k]=0;
      for(int k=0;k<MAXIT;k++)  ctrl[C_NEWA+k]=0;
      ctrl[C_FS+0]=1;
      ((float*)ctrl)[C_LOSS]=0.f;
      fr0[0]=root;
    }
  }
}

__global__ void k_frontier(const int* __restrict__ rowptrS, const int* __restrict__ colS,
                           int* __restrict__ hop, const int* __restrict__ frCur,
                           int* __restrict__ frNext, int* __restrict__ ctrl, int it, int N){
  if(ctrl[C_DONE]) return;
  int fs = ctrl[C_FS+it];
  int lvl = it+1;
  int i=blockIdx.x*BS+threadIdx.x, st=gridDim.x*BS;
  for(int f=i; f<fs; f+=st){
    int s=frCur[f];
    int b=rowptrS[s], e=rowptrS[s+1];
    for(int j=b;j<e;j++){
      int d=colS[j];
      if(d==s) continue;
      if(hop[d]==N){
        if(atomicCAS(&hop[d], N, lvl)==N){
          int p=atomicAdd(&ctrl[C_NEWA+it],1);
          frNext[p]=d;
        }
      }
    }
  }
}

__global__ void k_fin(int* __restrict__ hop, const int* __restrict__ perm,
                      int* __restrict__ frNext, int* __restrict__ ctrl,
                      int N, int target, int it){
  if(ctrl[C_DONE]) return;
  int newly = ctrl[C_NEWA+it];
  if(newly != 0){
    if(blockIdx.x==0 && threadIdx.x==0){
      int c = ctrl[C_CNT] + newly;
      ctrl[C_CNT]=c; ctrl[C_FS+it+1]=newly;
      if(c>target) ctrl[C_DONE]=1;
    }
    return;
  }
  // stuck: seed unreached node with min perm value (rare path)
  __shared__ unsigned long long sk[BS];
  int t=threadIdx.x;
  unsigned long long key=~0ull;
  for(int v=blockIdx.x*BS+t; v<N; v+=gridDim.x*BS)
    if(hop[v]==N){
      unsigned long long k=((unsigned long long)(unsigned)perm[v]<<32)|(unsigned)v;
      if(k<key) key=k;
    }
  sk[t]=key; __syncthreads();
  for(int o=BS/2;o>0;o>>=1){ if(t<o && sk[t+o]<sk[t]) sk[t]=sk[t+o]; __syncthreads(); }
  if(t==0){
    atomicMin((unsigned long long*)&ctrl[C_KEY], sk[0]);
    __threadfence();
    if(atomicAdd(&ctrl[C_BLK],1)==(int)gridDim.x-1){
      __threadfence();
      unsigned long long k=atomicAdd((unsigned long long*)&ctrl[C_KEY],0ull);
      int c=ctrl[C_CNT], fsz=0;
      if(k!=~0ull){
        int idx=(int)(k&0xffffffffu);
        hop[idx]=it+1;
        frNext[0]=idx;
        fsz=1; c+=1;
      }
      ctrl[C_CNT]=c; ctrl[C_FS+it+1]=fsz;
      *(unsigned long long*)&ctrl[C_KEY]=~0ull;
      ctrl[C_BLK]=0;
      if(c>target) ctrl[C_DONE]=1;
    }
  }
}

// ---------------- keep-mask (exact top-target by (hop, perm)) ----------------
__global__ void k_hop_hist(const int* __restrict__ hop, int N, int* __restrict__ hist){
  __shared__ int lh[64];
  int t=threadIdx.x;
  if(t<64) lh[t]=0;
  __syncthreads();
  int i=blockIdx.x*BS+t, st=gridDim.x*BS;
  for(int v=i;v<N;v+=st) atomicAdd(&lh[min(hop[v],63)],1);
  __syncthreads();
  if(t<64) atomicAdd(&hist[t], lh[t]);
}

__global__ void k_cutoff(const int* __restrict__ hist, int* __restrict__ ctrl, int target){
  if(blockIdx.x||threadIdx.x) return;
  int c=0, hstar=63, r=0;
  for(int h=0;h<64;h++){
    int x=hist[h];
    if(c+x>target){ hstar=h; r=target-c; break; }
    c+=x;
  }
  ctrl[C_HSTAR]=hstar; ctrl[C_R]=r;
}

__global__ void k_flagbits(const int* __restrict__ hop, const int* __restrict__ perm,
                           unsigned* __restrict__ bits, int N, const int* __restrict__ ctrl){
  int hstar=ctrl[C_HSTAR];
  int i=blockIdx.x*BS+threadIdx.x, st=gridDim.x*BS;
  for(int v=i;v<N;v+=st)
    if(min(hop[v],63)==hstar){ int p=perm[v]; atomicOr(&bits[p>>5], 1u<<(p&31)); }
}

// exclusive prefix of per-word popcounts (single block)
__global__ void k_scan_words(const unsigned* __restrict__ bits, int nw, int* __restrict__ wordpref){
  __shared__ int s[BS];
  __shared__ int carry;
  int t=threadIdx.x;
  if(t==0) carry=0;
  __syncthreads();
  for(int base=0; base<nw; base+=BS){
    int i=base+t;
    int v=(i<nw)? __popc(bits[i]) : 0;
    s[t]=v; __syncthreads();
    for(int o=1;o<BS;o<<=1){
      int x=(t>=o)? s[t-o]:0;
      __syncthreads();
      if(t>=o) s[t]+=x;
      __syncthreads();
    }
    if(i<nw) wordpref[i]=carry+s[t]-v;
    __syncthreads();
    if(t==0) carry+=s[BS-1];
    __syncthreads();
  }
}

__global__ void k_keep(const int* __restrict__ hop, const int* __restrict__ perm,
                       const unsigned* __restrict__ bits, const int* __restrict__ wordpref,
                       int* __restrict__ keepPk, int N, const int* __restrict__ ctrl, int pi){
  int hstar=ctrl[C_HSTAR], r=ctrl[C_R];
  int i=blockIdx.x*BS+threadIdx.x, st=gridDim.x*BS;
  for(int v=i;v<N;v+=st){
    int h=min(hop[v],63), kp=0;
    if(h<hstar) kp=1;
    else if(h==hstar){
      int p=perm[v];
      unsigned mask=(2u<<(p&31))-1u;   // inclusive low mask, p&31==31 -> ~0u
      int cum=wordpref[p>>5]+__popc(bits[p>>5]&mask);
      kp=(cum<=r);
    }
    if(pi==0) keepPk[v]=kp; else keepPk[v]|=kp<<1;
  }
}

// ---------------- fused dual-subgraph GCN + on-the-fly summaries ----------------
__global__ void k_subagg2(const int* __restrict__ rowptr, const int* __restrict__ col,
                          const fp8* __restrict__ FW, const int* __restrict__ keepPk,
                          float* __restrict__ sp1, float* __restrict__ sp2, int N){
  __shared__ float sh1[4][64], sh2[4][64];
  int t=threadIdx.x, lane=t&63, w=t>>6;
  int wid=(blockIdx.x*BS+t)>>6, nw=(gridDim.x*BS)>>6;
  float acc1=0.f, acc2=0.f;
  for(int v=wid; v<N; v+=nw){
    int kv=keepPk[v];
    if(!kv) continue;
    int b=rowptr[v], e=rowptr[v+1];
    float a1=0.f, a2=0.f; int c1=0, c2=0;
    int i=b;
    for(; i+2<=e; i+=2){
      int s0=col[i], s1=col[i+1];
      int k0=keepPk[s0], k1=keepPk[s1];
      float f0=(float)FW[s0*64+lane];
      float f1=(float)FW[s1*64+lane];
      a1 += (k0&1)? f0:0.f;  a2 += (k0&2)? f0:0.f;
      a1 += (k1&1)? f1:0.f;  a2 += (k1&2)? f1:0.f;
      c1 += (k0&1)+(k1&1);   c2 += ((k0>>1)&1)+((k1>>1)&1);
    }
    for(; i<e; i++){
      int s0=col[i]; int k0=keepPk[s0];
      float f0=(float)FW[s0*64+lane];
      a1 += (k0&1)? f0:0.f; a2 += (k0&2)? f0:0.f;
      c1 += k0&1; c2 += (k0>>1)&1;
    }
    if(kv&1) acc1 += fmaxf(a1/(float)max(c1,1),0.f);
    if(kv&2) acc2 += fmaxf(a2/(float)max(c2,1),0.f);
  }
  sh1[w][lane]=acc1; sh2[w][lane]=acc2;
  __syncthreads();
  if(w==0){
    sp1[blockIdx.x*64+lane]=sh1[0][lane]+sh1[1][lane]+sh1[2][lane]+sh1[3][lane];
    sp2[blockIdx.x*64+lane]=sh2[0][lane]+sh2[1][lane]+sh2[2][lane]+sh2[3][lane];
  }
}

__global__ void k_reduce2(const float* __restrict__ sp1, const float* __restrict__ sp2,
                          int nb, float* __restrict__ cf){
  __shared__ float s[BS];
  int t=threadIdx.x, d=t&63, p=t>>6;
  float a=0.f;
  for(int b=p;b<nb;b+=4) a+=sp1[b*64+d];
  s[t]=a; __syncthreads();
  if(t<64) cf[C_SUM1+t]=s[t]+s[t+64]+s[t+128]+s[t+192];
  __syncthreads();
  a=0.f;
  for(int b=p;b<nb;b+=4) a+=sp2[b*64+d];
  s[t]=a; __syncthreads();
  if(t<64) cf[C_SUM2+t]=s[t]+s[t+64]+s[t+128]+s[t+192];
}

__global__ void k_sumv(const float* __restrict__ Wd, float* __restrict__ cf,
                       int sumoff, int voff, float invk){
  __shared__ float s[64];
  int t=threadIdx.x;
  if(t<64){
    float x=cf[sumoff+t]*invk;
    s[t]=1.f/(1.f+expf(-x));
  }
  __syncthreads();
  if(t<64){
    float a=0.f;
    #pragma unroll
    for(int d=0;d<64;d++) a+=Wd[t*64+d]*s[d];
    cf[voff+t]=a;
  }
}

// ---------------- fused pos/neg GCN + BCE loss ----------------
__global__ void k_pnl(const int* __restrict__ rowptr, const int* __restrict__ col,
                      const fp8* __restrict__ FW, const fp8* __restrict__ FWn,
                      float* __restrict__ cf, int N){
  int t=threadIdx.x, lane=t&63, w=t>>6;
  float v1=cf[C_V1+lane], v2=cf[C_V2+lane];
  int wid=(blockIdx.x*BS+t)>>6, nw=(gridDim.x*BS)>>6;
  float acc=0.f;
  for(int v=wid; v<N; v+=nw){
    int b=rowptr[v], e=rowptr[v+1];
    float ap=0.f, an=0.f;
    int i=b;
    for(; i+4<=e; i+=4){
      int s0=col[i], s1=col[i+1], s2=col[i+2], s3=col[i+3];
      float p0=(float)FW[s0*64+lane],  q0=(float)FWn[s0*64+lane];
      float p1=(float)FW[s1*64+lane],  q1=(float)FWn[s1*64+lane];
      float p2=(float)FW[s2*64+lane],  q2=(float)FWn[s2*64+lane];
      float p3=(float)FW[s3*64+lane],  q3=(float)FWn[s3*64+lane];
      ap += (p0+p1)+(p2+p3);
      an += (q0+q1)+(q2+q3);
    }
    for(; i<e; i++){
      int s=col[i];
      ap += (float)FW[s*64+lane];
      an += (float)FWn[s*64+lane];
    }
    float inv=1.f/(float)max(e-b,1);
    float p=fmaxf(ap*inv,0.f), q=fmaxf(an*inv,0.f);
    float a1=p*v1, a2=p*v2, b1=q*v1, b2=q*v2;
    #pragma unroll
    for(int o=1;o<64;o<<=1){
      a1+=__shfl_xor(a1,o); a2+=__shfl_xor(a2,o);
      b1+=__shfl_xor(b1,o); b2+=__shfl_xor(b2,o);
    }
    if(lane==0) acc += softplusf(-a1)+softplusf(b1)+softplusf(-a2)+softplusf(b2);
  }
  __shared__ float s[4];
  if(lane==0) s[w]=acc;
  __syncthreads();
  if(t==0) atomicAdd(&cf[C_LOSS], s[0]+s[1]+s[2]+s[3]);
}

__global__ void k_final(const float* __restrict__ cf, float* __restrict__ out, int N){
  if(blockIdx.x||threadIdx.x) return;
  out[0]=cf[C_LOSS]/(float)N;
}

extern "C" void kernel_launch(void* const* d_in, const int* in_sizes, int n_in,
                              void* d_out, int out_size, void* d_ws, size_t ws_size,
                              hipStream_t stream) {
  const float* feat    = (const float*)d_in[0];
  const float* Wenc    = (const float*)d_in[1];
  const float* Wdisc   = (const float*)d_in[2];
  const int*   src     = (const int*)d_in[3];
  const int*   dst     = (const int*)d_in[4];
  const int*   permneg = (const int*)d_in[5];
  const int*   perm1   = (const int*)d_in[6];
  const int*   perm2   = (const int*)d_in[7];
  float* out = (float*)d_out;

  int N = in_sizes[5];
  int E = in_sizes[3];
  int target = (int)((double)N*0.8);
  int NB = (N+BS-1)/BS;
  int WORDS = (N+31)/32;
  int gE = (E+BS-1)/BS; if(gE>4096) gE=4096;
  const int SUBB = 4096;
  const int FB = 256, FINB = 128;

  // workspace carve (256B-aligned chunks)
  char* w = (char*)d_ws;
  auto alloc = [&](size_t bytes)->void*{
    void* p = (void*)w;
    w += (bytes + 255) & ~(size_t)255;
    return p;
  };
  int*      ctrl    = (int*)     alloc(4096);
  int*      cntD    = (int*)     alloc((size_t)N*4);
  int*      cntS    = (int*)     alloc((size_t)N*4);
  int*      rowptrD = (int*)     alloc((size_t)(N+1)*4);
  int*      rowptrS = (int*)     alloc((size_t)(N+1)*4);
  int*      curD    = (int*)     alloc((size_t)N*4);
  int*      curS    = (int*)     alloc((size_t)N*4);
  int*      colD    = (int*)     alloc((size_t)E*4);
  int*      colS    = (int*)     alloc((size_t)E*4);
  int*      hop     = (int*)     alloc((size_t)N*4);
  int*      keepPk  = (int*)     alloc((size_t)N*4);
  unsigned* bits    = (unsigned*)alloc((size_t)WORDS*4);
  int*      wordpref= (int*)     alloc((size_t)(WORDS+1)*4);
  int*      fr0     = (int*)     alloc((size_t)N*4);
  int*      fr1     = (int*)     alloc((size_t)N*4);
  int*      part    = (int*)     alloc((size_t)(NB+2)*4);
  int*      hist    = (int*)     alloc(64*4);
  fp8*      FW      = (fp8*)     alloc((size_t)N*64);
  fp8*      FWn     = (fp8*)     alloc((size_t)N*64);
  float*    sp1     = (float*)   alloc((size_t)SUBB*64*4);
  float*    sp2     = (float*)   alloc((size_t)SUBB*64*4);
  float*    cf = (float*)ctrl;

  // --- build both CSRs ---
  k_zero2     <<<NB, BS, 0, stream>>>(cntD, cntS, N);
  k_deg2      <<<gE, BS, 0, stream>>>(src, dst, E, cntS, cntD);
  k_blocksum  <<<NB, BS, 0, stream>>>(cntD, N, part);
  k_scan_block<<<1,  BS, 0, stream>>>(part, NB);
  k_rowptr    <<<NB, BS, 0, stream>>>(cntD, part, N, NB, rowptrD, curD);
  k_blocksum  <<<NB, BS, 0, stream>>>(cntS, N, part);
  k_scan_block<<<1,  BS, 0, stream>>>(part, NB);
  k_rowptr    <<<NB, BS, 0, stream>>>(cntS, part, N, NB, rowptrS, curS);
  k_scatter2  <<<gE, BS, 0, stream>>>(src, dst, E, curD, colD, curS, colS);

  // --- FW = feat @ W_enc (fp8), FWn = FW[perm_neg] ---
  k_fw      <<<2048, BS, 0, stream>>>(feat, Wenc, FW, N);
  k_permrows<<<4096, BS, 0, stream>>>((const unsigned*)FW, permneg, (unsigned*)FWn, N);

  const int* perms[2] = {perm1, perm2};
  for(int pi=0; pi<2; pi++){
    const int* perm = perms[pi];
    k_bfs_init<<<NB, BS, 0, stream>>>(hop, N, perm, ctrl, hist, fr0);
    for(int it=0; it<MAXIT; it++){
      int* frCur = (it&1)? fr1 : fr0;
      int* frNext= (it&1)? fr0 : fr1;
      k_frontier<<<FB,   BS, 0, stream>>>(rowptrS, colS, hop, frCur, frNext, ctrl, it, N);
      k_fin     <<<FINB, BS, 0, stream>>>(hop, perm, frNext, ctrl, N, target, it);
    }
    k_hop_hist  <<<512, BS, 0, stream>>>(hop, N, hist);
    k_cutoff    <<<1, 1, 0, stream>>>(hist, ctrl, target);
    k_zero1     <<<16, BS, 0, stream>>>((int*)bits, WORDS);
    k_flagbits  <<<NB, BS, 0, stream>>>(hop, perm, bits, N, ctrl);
    k_scan_words<<<1,  BS, 0, stream>>>(bits, WORDS, wordpref);
    k_keep      <<<NB, BS, 0, stream>>>(hop, perm, bits, wordpref, keepPk, N, ctrl, pi);
  }

  // --- fused dual subgraph GCN + summaries ---
  k_subagg2<<<SUBB, BS, 0, stream>>>(rowptrD, colD, FW, keepPk, sp1, sp2, N);
  k_reduce2<<<1, BS, 0, stream>>>(sp1, sp2, SUBB, cf);
  k_sumv   <<<1, 64, 0, stream>>>(Wdisc, cf, C_SUM1, C_V1, 1.f/(float)target);
  k_sumv   <<<1, 64, 0, stream>>>(Wdisc, cf, C_SUM2, C_V2, 1.f/(float)target);

  // --- fused pos/neg GCN + loss ---
  k_pnl  <<<(N+3)/4, BS, 0, stream>>>(rowptrD, colD, FW, FWn, cf, N);
  k_final<<<1, 1, 0, stream>>>(cf, out, N);
}

// Round 4
// 1524.682 us; speedup vs baseline: 1.5858x; 1.3110x over previous
//
#include <hip/hip_runtime.h>
#include <hip/hip_fp8.h>

#define BS 256
#define MAXIT 8

// ctrl int-index layout (ctrl is 256B-aligned, 4096B)
#define C_DONE  0
#define C_CNT   1
#define C_BLK   2
#define C_HSTAR 3
#define C_R     4
#define C_KEY   6   // unsigned long long @ ints [6],[7]
#define C_FS    8   // frontier-size slots [it], 8..18
#define C_NEWA  20  // newly-claimed slots [it], 20..29
#define C_LOSS  32  // float
#define C_SUM1  64  // float[64]
#define C_SUM2  128 // float[64]
#define C_V1    192 // float[64]
#define C_V2    256 // float[64]

typedef __hip_fp8_e4m3 fp8;

__device__ inline float softplusf(float x){
  return fmaxf(x, 0.f) + log1pf(expf(-fabsf(x)));
}

// ---------------- CSR build ----------------
__global__ void k_zero2(int* a, int* b, int n){
  int i=blockIdx.x*BS+threadIdx.x, st=gridDim.x*BS;
  for(; i<n; i+=st){ a[i]=0; b[i]=0; }
}

__global__ void k_zero1(int* a, int n){
  int i=blockIdx.x*BS+threadIdx.x, st=gridDim.x*BS;
  for(; i<n; i+=st) a[i]=0;
}

__global__ void k_deg2(const int* __restrict__ src, const int* __restrict__ dst, int E,
                       int* __restrict__ cntS, int* __restrict__ cntD){
  int i=blockIdx.x*BS+threadIdx.x, st=gridDim.x*BS;
  for(; i<E; i+=st){ atomicAdd(&cntS[src[i]],1); atomicAdd(&cntD[dst[i]],1); }
}

__global__ void k_blocksum(const int* __restrict__ a, int n, int* __restrict__ part){
  __shared__ int s[BS];
  int t=threadIdx.x, i=blockIdx.x*BS+t;
  s[t] = (i<n)? a[i] : 0;
  __syncthreads();
  for(int o=BS/2;o>0;o>>=1){ if(t<o) s[t]+=s[t+o]; __syncthreads(); }
  if(t==0) part[blockIdx.x]=s[0];
}

// single-block parallel exclusive scan (in place), total at a[n]
__global__ void k_scan_block(int* a, int n){
  __shared__ int s[BS];
  __shared__ int carry;
  int t=threadIdx.x;
  if(t==0) carry=0;
  __syncthreads();
  for(int base=0; base<n; base+=BS){
    int i=base+t;
    int v=(i<n)? a[i] : 0;
    s[t]=v; __syncthreads();
    for(int o=1;o<BS;o<<=1){
      int x=(t>=o)? s[t-o]:0;
      __syncthreads();
      if(t>=o) s[t]+=x;
      __syncthreads();
    }
    if(i<n) a[i]=carry+s[t]-v;
    __syncthreads();
    if(t==0) carry+=s[BS-1];
    __syncthreads();
  }
  if(t==0) a[n]=carry;
}

__global__ void k_rowptr(const int* __restrict__ cnt, const int* __restrict__ part, int n, int nb,
                         int* __restrict__ rowptr, int* __restrict__ cursor){
  __shared__ int s[BS];
  int b=blockIdx.x, t=threadIdx.x, i=b*BS+t;
  int v=(i<n)?cnt[i]:0;
  s[t]=v; __syncthreads();
  for(int o=1;o<BS;o<<=1){
    int x=(t>=o)? s[t-o]:0;
    __syncthreads();
    if(t>=o) s[t]+=x;
    __syncthreads();
  }
  int excl = s[t]-v+part[b];
  if(i<n){ rowptr[i]=excl; cursor[i]=excl; }
  if(b==0&&t==0) rowptr[n]=part[nb];
}

__global__ void k_scatter2(const int* __restrict__ src, const int* __restrict__ dst, int E,
                           int* __restrict__ curD, int* __restrict__ colD,
                           int* __restrict__ curS, int* __restrict__ colS){
  int i=blockIdx.x*BS+threadIdx.x, st=gridDim.x*BS;
  for(; i<E; i+=st){
    int s=src[i], d=dst[i];
    colD[atomicAdd(&curD[d],1)] = s;   // in-edges:  col = src
    colS[atomicAdd(&curS[s],1)] = d;   // out-edges: col = dst
  }
}

// ---------------- FW = feat @ W_enc  (fp8 e4m3 output) ----------------
__global__ void k_fw(const float* __restrict__ feat, const float* __restrict__ W,
                     fp8* __restrict__ FW, int N){
  __shared__ float sW[64*64];
  __shared__ float sf[4][64];
  int t=threadIdx.x;
  for(int i=t;i<64*64;i+=BS) sW[i]=W[i];
  __syncthreads();
  int j=t&63, r=t>>6;
  int ngroups=(N+3)>>2;
  for(int g=blockIdx.x; g<ngroups; g+=gridDim.x){
    int vr=g*4+r;
    sf[r][j] = (vr<N)? feat[vr*64+j] : 0.f;
    __syncthreads();
    if(vr<N){
      float acc=0.f;
      #pragma unroll
      for(int d=0;d<64;d++) acc += sf[r][d]*sW[d*64+j];
      FW[vr*64+j]=fp8(acc);
    }
    __syncthreads();
  }
}

// FWn[v] = FW[perm_neg[v]]  (row permute, 16 dwords per 64B row)
__global__ void k_permrows(const unsigned* __restrict__ FW, const int* __restrict__ pn,
                           unsigned* __restrict__ FWn, int N){
  int i=blockIdx.x*BS+threadIdx.x, st=gridDim.x*BS;
  int tot=N*16;
  for(; i<tot; i+=st){
    int v=i>>4, e=i&15;
    FWn[i]=FW[pn[v]*16+e];
  }
}

// ---------------- frontier BFS ----------------
__global__ void k_bfs_init(int* __restrict__ hop, int N, const int* __restrict__ perm,
                           int* __restrict__ ctrl, int* __restrict__ hist, int* __restrict__ fr0){
  int i=blockIdx.x*BS+threadIdx.x, st=gridDim.x*BS;
  int root=perm[0];
  for(int v=i;v<N;v+=st) hop[v]=(v==root)?0:N;
  if(blockIdx.x==0){
    if(threadIdx.x<64) hist[threadIdx.x]=0;
    if(threadIdx.x==0){
      ctrl[C_DONE]=0; ctrl[C_CNT]=1; ctrl[C_BLK]=0;
      *(unsigned long long*)&ctrl[C_KEY]=~0ull;
      for(int k=0;k<=MAXIT;k++) ctrl[C_FS+k]=0;
      for(int k=0;k<MAXIT;k++)  ctrl[C_NEWA+k]=0;
      ctrl[C_FS+0]=1;
      ((float*)ctrl)[C_LOSS]=0.f;
      fr0[0]=root;
    }
  }
}

__global__ void k_frontier(const int* __restrict__ rowptrS, const int* __restrict__ colS,
                           int* __restrict__ hop, const int* __restrict__ frCur,
                           int* __restrict__ frNext, int* __restrict__ ctrl, int it, int N){
  if(ctrl[C_DONE]) return;
  int fs = ctrl[C_FS+it];
  int lvl = it+1;
  int i=blockIdx.x*BS+threadIdx.x, st=gridDim.x*BS;
  for(int f=i; f<fs; f+=st){
    int s=frCur[f];
    int b=rowptrS[s], e=rowptrS[s+1];
    for(int j=b;j<e;j++){
      int d=colS[j];
      if(d==s) continue;
      if(hop[d]==N){
        if(atomicCAS(&hop[d], N, lvl)==N){
          int p=atomicAdd(&ctrl[C_NEWA+it],1);
          frNext[p]=d;
        }
      }
    }
  }
}

__global__ void k_fin(int* __restrict__ hop, const int* __restrict__ perm,
                      int* __restrict__ frNext, int* __restrict__ ctrl,
                      int N, int target, int it){
  if(ctrl[C_DONE]) return;
  int newly = ctrl[C_NEWA+it];
  if(newly != 0){
    if(blockIdx.x==0 && threadIdx.x==0){
      int c = ctrl[C_CNT] + newly;
      ctrl[C_CNT]=c; ctrl[C_FS+it+1]=newly;
      if(c>target) ctrl[C_DONE]=1;
    }
    return;
  }
  // stuck: seed unreached node with min perm value (rare path)
  __shared__ unsigned long long sk[BS];
  int t=threadIdx.x;
  unsigned long long key=~0ull;
  for(int v=blockIdx.x*BS+t; v<N; v+=gridDim.x*BS)
    if(hop[v]==N){
      unsigned long long k=((unsigned long long)(unsigned)perm[v]<<32)|(unsigned)v;
      if(k<key) key=k;
    }
  sk[t]=key; __syncthreads();
  for(int o=BS/2;o>0;o>>=1){ if(t<o && sk[t+o]<sk[t]) sk[t]=sk[t+o]; __syncthreads(); }
  if(t==0){
    atomicMin((unsigned long long*)&ctrl[C_KEY], sk[0]);
    __threadfence();
    if(atomicAdd(&ctrl[C_BLK],1)==(int)gridDim.x-1){
      __threadfence();
      unsigned long long k=atomicAdd((unsigned long long*)&ctrl[C_KEY],0ull);
      int c=ctrl[C_CNT], fsz=0;
      if(k!=~0ull){
        int idx=(int)(k&0xffffffffu);
        hop[idx]=it+1;
        frNext[0]=idx;
        fsz=1; c+=1;
      }
      ctrl[C_CNT]=c; ctrl[C_FS+it+1]=fsz;
      *(unsigned long long*)&ctrl[C_KEY]=~0ull;
      ctrl[C_BLK]=0;
      if(c>target) ctrl[C_DONE]=1;
    }
  }
}

// ---------------- keep-mask (exact top-target by (hop, perm)) ----------------
__global__ void k_hop_hist(const int* __restrict__ hop, int N, int* __restrict__ hist){
  __shared__ int lh[64];
  int t=threadIdx.x;
  if(t<64) lh[t]=0;
  __syncthreads();
  int i=blockIdx.x*BS+t, st=gridDim.x*BS;
  for(int v=i;v<N;v+=st) atomicAdd(&lh[min(hop[v],63)],1);
  __syncthreads();
  if(t<64) atomicAdd(&hist[t], lh[t]);
}

__global__ void k_cutoff(const int* __restrict__ hist, int* __restrict__ ctrl, int target){
  if(blockIdx.x||threadIdx.x) return;
  int c=0, hstar=63, r=0;
  for(int h=0;h<64;h++){
    int x=hist[h];
    if(c+x>target){ hstar=h; r=target-c; break; }
    c+=x;
  }
  ctrl[C_HSTAR]=hstar; ctrl[C_R]=r;
}

__global__ void k_flagbits(const int* __restrict__ hop, const int* __restrict__ perm,
                           unsigned* __restrict__ bits, int N, const int* __restrict__ ctrl){
  int hstar=ctrl[C_HSTAR];
  int i=blockIdx.x*BS+threadIdx.x, st=gridDim.x*BS;
  for(int v=i;v<N;v+=st)
    if(min(hop[v],63)==hstar){ int p=perm[v]; atomicOr(&bits[p>>5], 1u<<(p&31)); }
}

// exclusive prefix of per-word popcounts (single block)
__global__ void k_scan_words(const unsigned* __restrict__ bits, int nw, int* __restrict__ wordpref){
  __shared__ int s[BS];
  __shared__ int carry;
  int t=threadIdx.x;
  if(t==0) carry=0;
  __syncthreads();
  for(int base=0; base<nw; base+=BS){
    int i=base+t;
    int v=(i<nw)? __popc(bits[i]) : 0;
    s[t]=v; __syncthreads();
    for(int o=1;o<BS;o<<=1){
      int x=(t>=o)? s[t-o]:0;
      __syncthreads();
      if(t>=o) s[t]+=x;
      __syncthreads();
    }
    if(i<nw) wordpref[i]=carry+s[t]-v;
    __syncthreads();
    if(t==0) carry+=s[BS-1];
    __syncthreads();
  }
}

__global__ void k_keep(const int* __restrict__ hop, const int* __restrict__ perm,
                       const unsigned* __restrict__ bits, const int* __restrict__ wordpref,
                       int* __restrict__ keepPk, int N, const int* __restrict__ ctrl, int pi){
  int hstar=ctrl[C_HSTAR], r=ctrl[C_R];
  int i=blockIdx.x*BS+threadIdx.x, st=gridDim.x*BS;
  for(int v=i;v<N;v+=st){
    int h=min(hop[v],63), kp=0;
    if(h<hstar) kp=1;
    else if(h==hstar){
      int p=perm[v];
      unsigned mask=(2u<<(p&31))-1u;   // inclusive low mask, p&31==31 -> ~0u
      int cum=wordpref[p>>5]+__popc(bits[p>>5]&mask);
      kp=(cum<=r);
    }
    if(pi==0) keepPk[v]=kp; else keepPk[v]|=kp<<1;
  }
}

// ---------------- fused dual-subgraph GCN + on-the-fly summaries ----------------
__global__ void k_subagg2(const int* __restrict__ rowptr, const int* __restrict__ col,
                          const fp8* __restrict__ FW, const int* __restrict__ keepPk,
                          float* __restrict__ sp1, float* __restrict__ sp2, int N){
  __shared__ float sh1[4][64], sh2[4][64];
  int t=threadIdx.x, lane=t&63, w=t>>6;
  int wid=(blockIdx.x*BS+t)>>6, nw=(gridDim.x*BS)>>6;
  float acc1=0.f, acc2=0.f;
  for(int v=wid; v<N; v+=nw){
    int kv=keepPk[v];
    if(!kv) continue;
    int b=rowptr[v], e=rowptr[v+1];
    float a1=0.f, a2=0.f; int c1=0, c2=0;
    int i=b;
    for(; i+2<=e; i+=2){
      int s0=col[i], s1=col[i+1];
      int k0=keepPk[s0], k1=keepPk[s1];
      float f0=(float)FW[s0*64+lane];
      float f1=(float)FW[s1*64+lane];
      a1 += (k0&1)? f0:0.f;  a2 += (k0&2)? f0:0.f;
      a1 += (k1&1)? f1:0.f;  a2 += (k1&2)? f1:0.f;
      c1 += (k0&1)+(k1&1);   c2 += ((k0>>1)&1)+((k1>>1)&1);
    }
    for(; i<e; i++){
      int s0=col[i]; int k0=keepPk[s0];
      float f0=(float)FW[s0*64+lane];
      a1 += (k0&1)? f0:0.f; a2 += (k0&2)? f0:0.f;
      c1 += k0&1; c2 += (k0>>1)&1;
    }
    if(kv&1) acc1 += fmaxf(a1/(float)max(c1,1),0.f);
    if(kv&2) acc2 += fmaxf(a2/(float)max(c2,1),0.f);
  }
  sh1[w][lane]=acc1; sh2[w][lane]=acc2;
  __syncthreads();
  if(w==0){
    sp1[blockIdx.x*64+lane]=sh1[0][lane]+sh1[1][lane]+sh1[2][lane]+sh1[3][lane];
    sp2[blockIdx.x*64+lane]=sh2[0][lane]+sh2[1][lane]+sh2[2][lane]+sh2[3][lane];
  }
}

// stage 1: 128 blocks, block b reduces rows [b*rows, (b+1)*rows) of sp1/sp2
__global__ void k_reduce_s1(const float* __restrict__ sp1, const float* __restrict__ sp2,
                            int nb, int rows, float* __restrict__ sp1b, float* __restrict__ sp2b){
  __shared__ float s[BS];
  int t=threadIdx.x, lane=t&63, p=t>>6;
  int base=blockIdx.x*rows;
  float a=0.f;
  for(int r=p; r<rows; r+=4){
    int row=base+r;
    if(row<nb) a+=sp1[row*64+lane];
  }
  s[t]=a; __syncthreads();
  if(t<64) sp1b[blockIdx.x*64+t]=s[t]+s[t+64]+s[t+128]+s[t+192];
  __syncthreads();
  a=0.f;
  for(int r=p; r<rows; r+=4){
    int row=base+r;
    if(row<nb) a+=sp2[row*64+lane];
  }
  s[t]=a; __syncthreads();
  if(t<64) sp2b[blockIdx.x*64+t]=s[t]+s[t+64]+s[t+128]+s[t+192];
}

// stage 2: single block over nb2 (=128) rows
__global__ void k_reduce_s2(const float* __restrict__ sp1b, const float* __restrict__ sp2b,
                            int nb2, float* __restrict__ cf){
  __shared__ float s[BS];
  int t=threadIdx.x, lane=t&63, p=t>>6;
  float a=0.f;
  for(int b=p;b<nb2;b+=4) a+=sp1b[b*64+lane];
  s[t]=a; __syncthreads();
  if(t<64) cf[C_SUM1+t]=s[t]+s[t+64]+s[t+128]+s[t+192];
  __syncthreads();
  a=0.f;
  for(int b=p;b<nb2;b+=4) a+=sp2b[b*64+lane];
  s[t]=a; __syncthreads();
  if(t<64) cf[C_SUM2+t]=s[t]+s[t+64]+s[t+128]+s[t+192];
}

__global__ void k_sumv(const float* __restrict__ Wd, float* __restrict__ cf,
                       int sumoff, int voff, float invk){
  __shared__ float s[64];
  int t=threadIdx.x;
  if(t<64){
    float x=cf[sumoff+t]*invk;
    s[t]=1.f/(1.f+expf(-x));
  }
  __syncthreads();
  if(t<64){
    float a=0.f;
    #pragma unroll
    for(int d=0;d<64;d++) a+=Wd[t*64+d]*s[d];
    cf[voff+t]=a;
  }
}

// ---------------- fused pos/neg GCN + BCE loss ----------------
__global__ void k_pnl(const int* __restrict__ rowptr, const int* __restrict__ col,
                      const fp8* __restrict__ FW, const fp8* __restrict__ FWn,
                      float* __restrict__ cf, int N){
  int t=threadIdx.x, lane=t&63, w=t>>6;
  float v1=cf[C_V1+lane], v2=cf[C_V2+lane];
  int wid=(blockIdx.x*BS+t)>>6, nw=(gridDim.x*BS)>>6;
  float acc=0.f;
  for(int v=wid; v<N; v+=nw){
    int b=rowptr[v], e=rowptr[v+1];
    float ap=0.f, an=0.f;
    int i=b;
    for(; i+4<=e; i+=4){
      int s0=col[i], s1=col[i+1], s2=col[i+2], s3=col[i+3];
      float p0=(float)FW[s0*64+lane],  q0=(float)FWn[s0*64+lane];
      float p1=(float)FW[s1*64+lane],  q1=(float)FWn[s1*64+lane];
      float p2=(float)FW[s2*64+lane],  q2=(float)FWn[s2*64+lane];
      float p3=(float)FW[s3*64+lane],  q3=(float)FWn[s3*64+lane];
      ap += (p0+p1)+(p2+p3);
      an += (q0+q1)+(q2+q3);
    }
    for(; i<e; i++){
      int s=col[i];
      ap += (float)FW[s*64+lane];
      an += (float)FWn[s*64+lane];
    }
    float inv=1.f/(float)max(e-b,1);
    float p=fmaxf(ap*inv,0.f), q=fmaxf(an*inv,0.f);
    float a1=p*v1, a2=p*v2, b1=q*v1, b2=q*v2;
    #pragma unroll
    for(int o=1;o<64;o<<=1){
      a1+=__shfl_xor(a1,o); a2+=__shfl_xor(a2,o);
      b1+=__shfl_xor(b1,o); b2+=__shfl_xor(b2,o);
    }
    if(lane==0) acc += softplusf(-a1)+softplusf(b1)+softplusf(-a2)+softplusf(b2);
  }
  __shared__ float s[4];
  if(lane==0) s[w]=acc;
  __syncthreads();
  if(t==0) atomicAdd(&cf[C_LOSS], s[0]+s[1]+s[2]+s[3]);
}

__global__ void k_final(const float* __restrict__ cf, float* __restrict__ out, int N){
  if(blockIdx.x||threadIdx.x) return;
  out[0]=cf[C_LOSS]/(float)N;
}

extern "C" void kernel_launch(void* const* d_in, const int* in_sizes, int n_in,
                              void* d_out, int out_size, void* d_ws, size_t ws_size,
                              hipStream_t stream) {
  const float* feat    = (const float*)d_in[0];
  const float* Wenc    = (const float*)d_in[1];
  const float* Wdisc   = (const float*)d_in[2];
  const int*   src     = (const int*)d_in[3];
  const int*   dst     = (const int*)d_in[4];
  const int*   permneg = (const int*)d_in[5];
  const int*   perm1   = (const int*)d_in[6];
  const int*   perm2   = (const int*)d_in[7];
  float* out = (float*)d_out;

  int N = in_sizes[5];
  int E = in_sizes[3];
  int target = (int)((double)N*0.8);
  int NB = (N+BS-1)/BS;
  int WORDS = (N+31)/32;
  int gE = (E+BS-1)/BS; if(gE>4096) gE=4096;
  const int SUBB = 4096;
  const int R1B = 128, R1ROWS = SUBB/R1B;
  const int FB = 256, FINB = 128;

  // workspace carve (256B-aligned chunks)
  char* w = (char*)d_ws;
  auto alloc = [&](size_t bytes)->void*{
    void* p = (void*)w;
    w += (bytes + 255) & ~(size_t)255;
    return p;
  };
  int*      ctrl    = (int*)     alloc(4096);
  int*      cntD    = (int*)     alloc((size_t)N*4);
  int*      cntS    = (int*)     alloc((size_t)N*4);
  int*      rowptrD = (int*)     alloc((size_t)(N+1)*4);
  int*      rowptrS = (int*)     alloc((size_t)(N+1)*4);
  int*      curD    = (int*)     alloc((size_t)N*4);
  int*      curS    = (int*)     alloc((size_t)N*4);
  int*      colD    = (int*)     alloc((size_t)E*4);
  int*      colS    = (int*)     alloc((size_t)E*4);
  int*      hop     = (int*)     alloc((size_t)N*4);
  int*      keepPk  = (int*)     alloc((size_t)N*4);
  unsigned* bits    = (unsigned*)alloc((size_t)WORDS*4);
  int*      wordpref= (int*)     alloc((size_t)(WORDS+1)*4);
  int*      fr0     = (int*)     alloc((size_t)N*4);
  int*      fr1     = (int*)     alloc((size_t)N*4);
  int*      part    = (int*)     alloc((size_t)(NB+2)*4);
  int*      hist    = (int*)     alloc(64*4);
  fp8*      FW      = (fp8*)     alloc((size_t)N*64);
  fp8*      FWn     = (fp8*)     alloc((size_t)N*64);
  float*    sp1     = (float*)   alloc((size_t)SUBB*64*4);
  float*    sp2     = (float*)   alloc((size_t)SUBB*64*4);
  float*    sp1b    = (float*)   alloc((size_t)R1B*64*4);
  float*    sp2b    = (float*)   alloc((size_t)R1B*64*4);
  float*    cf = (float*)ctrl;

  // --- build both CSRs ---
  k_zero2     <<<NB, BS, 0, stream>>>(cntD, cntS, N);
  k_deg2      <<<gE, BS, 0, stream>>>(src, dst, E, cntS, cntD);
  k_blocksum  <<<NB, BS, 0, stream>>>(cntD, N, part);
  k_scan_block<<<1,  BS, 0, stream>>>(part, NB);
  k_rowptr    <<<NB, BS, 0, stream>>>(cntD, part, N, NB, rowptrD, curD);
  k_blocksum  <<<NB, BS, 0, stream>>>(cntS, N, part);
  k_scan_block<<<1,  BS, 0, stream>>>(part, NB);
  k_rowptr    <<<NB, BS, 0, stream>>>(cntS, part, N, NB, rowptrS, curS);
  k_scatter2  <<<gE, BS, 0, stream>>>(src, dst, E, curD, colD, curS, colS);

  // --- FW = feat @ W_enc (fp8), FWn = FW[perm_neg] ---
  k_fw      <<<2048, BS, 0, stream>>>(feat, Wenc, FW, N);
  k_permrows<<<4096, BS, 0, stream>>>((const unsigned*)FW, permneg, (unsigned*)FWn, N);

  const int* perms[2] = {perm1, perm2};
  for(int pi=0; pi<2; pi++){
    const int* perm = perms[pi];
    k_bfs_init<<<NB, BS, 0, stream>>>(hop, N, perm, ctrl, hist, fr0);
    for(int it=0; it<MAXIT; it++){
      int* frCur = (it&1)? fr1 : fr0;
      int* frNext= (it&1)? fr0 : fr1;
      k_frontier<<<FB,   BS, 0, stream>>>(rowptrS, colS, hop, frCur, frNext, ctrl, it, N);
      k_fin     <<<FINB, BS, 0, stream>>>(hop, perm, frNext, ctrl, N, target, it);
    }
    k_hop_hist  <<<512, BS, 0, stream>>>(hop, N, hist);
    k_cutoff    <<<1, 1, 0, stream>>>(hist, ctrl, target);
    k_zero1     <<<16, BS, 0, stream>>>((int*)bits, WORDS);
    k_flagbits  <<<NB, BS, 0, stream>>>(hop, perm, bits, N, ctrl);
    k_scan_words<<<1,  BS, 0, stream>>>(bits, WORDS, wordpref);
    k_keep      <<<NB, BS, 0, stream>>>(hop, perm, bits, wordpref, keepPk, N, ctrl, pi);
  }

  // --- fused dual subgraph GCN + summaries (hierarchical reduce) ---
  k_subagg2  <<<SUBB, BS, 0, stream>>>(rowptrD, colD, FW, keepPk, sp1, sp2, N);
  k_reduce_s1<<<R1B, BS, 0, stream>>>(sp1, sp2, SUBB, R1ROWS, sp1b, sp2b);
  k_reduce_s2<<<1,   BS, 0, stream>>>(sp1b, sp2b, R1B, cf);
  k_sumv     <<<1, 64, 0, stream>>>(Wdisc, cf, C_SUM1, C_V1, 1.f/(float)target);
  k_sumv     <<<1, 64, 0, stream>>>(Wdisc, cf, C_SUM2, C_V2, 1.f/(float)target);

  // --- fused pos/neg GCN + loss ---
  k_pnl  <<<(N+3)/4, BS, 0, stream>>>(rowptrD, colD, FW, FWn, cf, N);
  k_final<<<1, 1, 0, stream>>>(cf, out, N);
}

// Round 6
// 1309.739 us; speedup vs baseline: 1.8461x; 1.1641x over previous
//
#include <hip/hip_runtime.h>
#include <hip/hip_fp8.h>
#include <hip/hip_fp16.h>

#define BS 256
#define MAXIT 8

// ctrl int-index layout (ctrl is 256B-aligned, 4096B)
#define C_DONE  0
#define C_CNT   1
#define C_BLK   2
#define C_HSTAR 3
#define C_R     4
#define C_KEY   6   // unsigned long long @ ints [6],[7]
#define C_FS    8   // frontier-size slots [it], 8..18
#define C_NEWA  20  // newly-claimed slots [it], 20..29
#define C_LOSS  32  // float
#define C_SUM1  64  // float[64]
#define C_SUM2  128 // float[64]
#define C_V1    192 // float[64]
#define C_V2    256 // float[64]

typedef __hip_fp8_e4m3 fp8;

__device__ inline float softplusf(float x){
  return fmaxf(x, 0.f) + log1pf(expf(-fabsf(x)));
}

// ---------------- CSR build ----------------
__global__ void k_zero2(int* a, int* b, int n){
  int i=blockIdx.x*BS+threadIdx.x, st=gridDim.x*BS;
  for(; i<n; i+=st){ a[i]=0; b[i]=0; }
}

__global__ void k_zero1(int* a, int n){
  int i=blockIdx.x*BS+threadIdx.x, st=gridDim.x*BS;
  for(; i<n; i+=st) a[i]=0;
}

__global__ void k_deg2(const int* __restrict__ src, const int* __restrict__ dst, int E,
                       int* __restrict__ cntS, int* __restrict__ cntD){
  int i=blockIdx.x*BS+threadIdx.x, st=gridDim.x*BS;
  for(; i<E; i+=st){ atomicAdd(&cntS[src[i]],1); atomicAdd(&cntD[dst[i]],1); }
}

__global__ void k_blocksum(const int* __restrict__ a, int n, int* __restrict__ part){
  __shared__ int s[BS];
  int t=threadIdx.x, i=blockIdx.x*BS+t;
  s[t] = (i<n)? a[i] : 0;
  __syncthreads();
  for(int o=BS/2;o>0;o>>=1){ if(t<o) s[t]+=s[t+o]; __syncthreads(); }
  if(t==0) part[blockIdx.x]=s[0];
}

// single-block parallel exclusive scan (in place), total at a[n]
__global__ void k_scan_block(int* a, int n){
  __shared__ int s[BS];
  __shared__ int carry;
  int t=threadIdx.x;
  if(t==0) carry=0;
  __syncthreads();
  for(int base=0; base<n; base+=BS){
    int i=base+t;
    int v=(i<n)? a[i] : 0;
    s[t]=v; __syncthreads();
    for(int o=1;o<BS;o<<=1){
      int x=(t>=o)? s[t-o]:0;
      __syncthreads();
      if(t>=o) s[t]+=x;
      __syncthreads();
    }
    if(i<n) a[i]=carry+s[t]-v;
    __syncthreads();
    if(t==0) carry+=s[BS-1];
    __syncthreads();
  }
  if(t==0) a[n]=carry;
}

__global__ void k_rowptr(const int* __restrict__ cnt, const int* __restrict__ part, int n, int nb,
                         int* __restrict__ rowptr, int* __restrict__ cursor){
  __shared__ int s[BS];
  int b=blockIdx.x, t=threadIdx.x, i=b*BS+t;
  int v=(i<n)?cnt[i]:0;
  s[t]=v; __syncthreads();
  for(int o=1;o<BS;o<<=1){
    int x=(t>=o)? s[t-o]:0;
    __syncthreads();
    if(t>=o) s[t]+=x;
    __syncthreads();
  }
  int excl = s[t]-v+part[b];
  if(i<n){ rowptr[i]=excl; cursor[i]=excl; }
  if(b==0&&t==0) rowptr[n]=part[nb];
}

__global__ void k_scatter2(const int* __restrict__ src, const int* __restrict__ dst, int E,
                           int* __restrict__ curD, int* __restrict__ colD,
                           int* __restrict__ curS, int* __restrict__ colS){
  int i=blockIdx.x*BS+threadIdx.x, st=gridDim.x*BS;
  for(; i<E; i+=st){
    int s=src[i], d=dst[i];
    colD[atomicAdd(&curD[d],1)] = s;   // in-edges:  col = src
    colS[atomicAdd(&curS[s],1)] = d;   // out-edges: col = dst
  }
}

// ---------------- FW = feat @ W_enc  (fp8 e4m3 output) ----------------
__global__ void k_fw(const float* __restrict__ feat, const float* __restrict__ W,
                     fp8* __restrict__ FW, int N){
  __shared__ float sW[64*64];
  __shared__ float sf[4][64];
  int t=threadIdx.x;
  for(int i=t;i<64*64;i+=BS) sW[i]=W[i];
  __syncthreads();
  int j=t&63, r=t>>6;
  int ngroups=(N+3)>>2;
  for(int g=blockIdx.x; g<ngroups; g+=gridDim.x){
    int vr=g*4+r;
    sf[r][j] = (vr<N)? feat[vr*64+j] : 0.f;
    __syncthreads();
    if(vr<N){
      float acc=0.f;
      #pragma unroll
      for(int d=0;d<64;d++) acc += sf[r][d]*sW[d*64+j];
      FW[vr*64+j]=fp8(acc);
    }
    __syncthreads();
  }
}

// FWn[v] = FW[perm_neg[v]]  (row permute, 16 dwords per 64B row)
__global__ void k_permrows(const unsigned* __restrict__ FW, const int* __restrict__ pn,
                           unsigned* __restrict__ FWn, int N){
  int i=blockIdx.x*BS+threadIdx.x, st=gridDim.x*BS;
  int tot=N*16;
  for(; i<tot; i+=st){
    int v=i>>4, e=i&15;
    FWn[i]=FW[pn[v]*16+e];
  }
}

// ---------------- frontier BFS ----------------
__global__ void k_bfs_init(int* __restrict__ hop, int N, const int* __restrict__ perm,
                           int* __restrict__ ctrl, int* __restrict__ hist, int* __restrict__ fr0){
  int i=blockIdx.x*BS+threadIdx.x, st=gridDim.x*BS;
  int root=perm[0];
  for(int v=i;v<N;v+=st) hop[v]=(v==root)?0:N;
  if(blockIdx.x==0){
    if(threadIdx.x<64) hist[threadIdx.x]=0;
    if(threadIdx.x==0){
      ctrl[C_DONE]=0; ctrl[C_CNT]=1; ctrl[C_BLK]=0;
      *(unsigned long long*)&ctrl[C_KEY]=~0ull;
      for(int k=0;k<=MAXIT;k++) ctrl[C_FS+k]=0;
      for(int k=0;k<MAXIT;k++)  ctrl[C_NEWA+k]=0;
      ctrl[C_FS+0]=1;
      ((float*)ctrl)[C_LOSS]=0.f;
      fr0[0]=root;
    }
  }
}

__global__ void k_frontier(const int* __restrict__ rowptrS, const int* __restrict__ colS,
                           int* __restrict__ hop, const int* __restrict__ frCur,
                           int* __restrict__ frNext, int* __restrict__ ctrl, int it, int N){
  if(ctrl[C_DONE]) return;
  int fs = ctrl[C_FS+it];
  int lvl = it+1;
  int i=blockIdx.x*BS+threadIdx.x, st=gridDim.x*BS;
  for(int f=i; f<fs; f+=st){
    int s=frCur[f];
    int b=rowptrS[s], e=rowptrS[s+1];
    for(int j=b;j<e;j++){
      int d=colS[j];
      if(d==s) continue;
      if(hop[d]==N){
        if(atomicCAS(&hop[d], N, lvl)==N){
          int p=atomicAdd(&ctrl[C_NEWA+it],1);
          frNext[p]=d;
        }
      }
    }
  }
}

__global__ void k_fin(int* __restrict__ hop, const int* __restrict__ perm,
                      int* __restrict__ frNext, int* __restrict__ ctrl,
                      int N, int target, int it){
  if(ctrl[C_DONE]) return;
  int newly = ctrl[C_NEWA+it];
  if(newly != 0){
    if(blockIdx.x==0 && threadIdx.x==0){
      int c = ctrl[C_CNT] + newly;
      ctrl[C_CNT]=c; ctrl[C_FS+it+1]=newly;
      if(c>target) ctrl[C_DONE]=1;
    }
    return;
  }
  // stuck: seed unreached node with min perm value (rare path)
  __shared__ unsigned long long sk[BS];
  int t=threadIdx.x;
  unsigned long long key=~0ull;
  for(int v=blockIdx.x*BS+t; v<N; v+=gridDim.x*BS)
    if(hop[v]==N){
      unsigned long long k=((unsigned long long)(unsigned)perm[v]<<32)|(unsigned)v;
      if(k<key) key=k;
    }
  sk[t]=key; __syncthreads();
  for(int o=BS/2;o>0;o>>=1){ if(t<o && sk[t+o]<sk[t]) sk[t]=sk[t+o]; __syncthreads(); }
  if(t==0){
    atomicMin((unsigned long long*)&ctrl[C_KEY], sk[0]);
    __threadfence();
    if(atomicAdd(&ctrl[C_BLK],1)==(int)gridDim.x-1){
      __threadfence();
      unsigned long long k=atomicAdd((unsigned long long*)&ctrl[C_KEY],0ull);
      int c=ctrl[C_CNT], fsz=0;
      if(k!=~0ull){
        int idx=(int)(k&0xffffffffu);
        hop[idx]=it+1;
        frNext[0]=idx;
        fsz=1; c+=1;
      }
      ctrl[C_CNT]=c; ctrl[C_FS+it+1]=fsz;
      *(unsigned long long*)&ctrl[C_KEY]=~0ull;
      ctrl[C_BLK]=0;
      if(c>target) ctrl[C_DONE]=1;
    }
  }
}

// ---------------- keep-mask (exact top-target by (hop, perm)) ----------------
__global__ void k_hop_hist(const int* __restrict__ hop, int N, int* __restrict__ hist){
  __shared__ int lh[64];
  int t=threadIdx.x;
  if(t<64) lh[t]=0;
  __syncthreads();
  int i=blockIdx.x*BS+t, st=gridDim.x*BS;
  for(int v=i;v<N;v+=st) atomicAdd(&lh[min(hop[v],63)],1);
  __syncthreads();
  if(t<64) atomicAdd(&hist[t], lh[t]);
}

__global__ void k_cutoff(const int* __restrict__ hist, int* __restrict__ ctrl, int target){
  if(blockIdx.x||threadIdx.x) return;
  int c=0, hstar=63, r=0;
  for(int h=0;h<64;h++){
    int x=hist[h];
    if(c+x>target){ hstar=h; r=target-c; break; }
    c+=x;
  }
  ctrl[C_HSTAR]=hstar; ctrl[C_R]=r;
}

__global__ void k_flagbits(const int* __restrict__ hop, const int* __restrict__ perm,
                           unsigned* __restrict__ bits, int N, const int* __restrict__ ctrl){
  int hstar=ctrl[C_HSTAR];
  int i=blockIdx.x*BS+threadIdx.x, st=gridDim.x*BS;
  for(int v=i;v<N;v+=st)
    if(min(hop[v],63)==hstar){ int p=perm[v]; atomicOr(&bits[p>>5], 1u<<(p&31)); }
}

// exclusive prefix of per-word popcounts (single block)
__global__ void k_scan_words(const unsigned* __restrict__ bits, int nw, int* __restrict__ wordpref){
  __shared__ int s[BS];
  __shared__ int carry;
  int t=threadIdx.x;
  if(t==0) carry=0;
  __syncthreads();
  for(int base=0; base<nw; base+=BS){
    int i=base+t;
    int v=(i<nw)? __popc(bits[i]) : 0;
    s[t]=v; __syncthreads();
    for(int o=1;o<BS;o<<=1){
      int x=(t>=o)? s[t-o]:0;
      __syncthreads();
      if(t>=o) s[t]+=x;
      __syncthreads();
    }
    if(i<nw) wordpref[i]=carry+s[t]-v;
    __syncthreads();
    if(t==0) carry+=s[BS-1];
    __syncthreads();
  }
}

__global__ void k_keep(const int* __restrict__ hop, const int* __restrict__ perm,
                       const unsigned* __restrict__ bits, const int* __restrict__ wordpref,
                       int* __restrict__ keepPk, int N, const int* __restrict__ ctrl, int pi){
  int hstar=ctrl[C_HSTAR], r=ctrl[C_R];
  int i=blockIdx.x*BS+threadIdx.x, st=gridDim.x*BS;
  for(int v=i;v<N;v+=st){
    int h=min(hop[v],63), kp=0;
    if(h<hstar) kp=1;
    else if(h==hstar){
      int p=perm[v];
      unsigned mask=(2u<<(p&31))-1u;   // inclusive low mask
      int cum=wordpref[p>>5]+__popc(bits[p>>5]&mask);
      kp=(cum<=r);
    }
    if(pi==0) keepPk[v]=kp; else keepPk[v]|=kp<<1;
  }
}

// ---------------- fused mega gather: pos/neg rows + both subgraph summaries ----------------
// lane L = (edge L>>2, 16-dim slice L&3); one dwordx4 gather covers 16 edges.
__global__ void __launch_bounds__(BS, 8) k_mega(
    const int* __restrict__ rowptr, const int* __restrict__ col,
    const unsigned char* __restrict__ FW8, const unsigned char* __restrict__ FWn8,
    const int* __restrict__ keepPk,
    __half* __restrict__ P, __half* __restrict__ Q,
    float* __restrict__ sp1, float* __restrict__ sp2, int N){
  __shared__ uint4 ldsA4[4][16][4];
  __shared__ uint4 ldsB4[4][16][4];
  __shared__ float sh1[4][64], sh2[4][64];
  int t=threadIdx.x, lane=t&63, w=t>>6;
  int eidx=lane>>2, q=lane&3;
  volatile unsigned char* lA=(volatile unsigned char*)&ldsA4[w][0][0];
  volatile unsigned char* lB=(volatile unsigned char*)&ldsB4[w][0][0];
  int wid=(blockIdx.x*BS+t)>>6, nw=(gridDim.x*BS)>>6;
  float acc1=0.f, acc2=0.f;
  for(int v=wid; v<N; v+=nw){
    int b=rowptr[v], e=rowptr[v+1];
    int deg=e-b;
    int kv=keepPk[v];
    float ap=0.f, an=0.f, a1=0.f, a2=0.f;
    int c1t=0, c2t=0;
    for(int c0=b; c0<e; c0+=16){
      int n=min(16, e-c0);
      uint4 wa=make_uint4(0,0,0,0), wb=make_uint4(0,0,0,0);
      int kk=0;
      if(eidx<n){
        int s=col[c0+eidx];
        kk=keepPk[s];
        size_t off=((size_t)s<<6)+(q<<4);
        wa=*reinterpret_cast<const uint4*>(FW8+off);
        wb=*reinterpret_cast<const uint4*>(FWn8+off);
      }
      // stage raw fp8 rows in wave-private LDS (component stores: volatile uint4 has no operator=)
      volatile unsigned* pa=(volatile unsigned*)&ldsA4[w][eidx][q];
      volatile unsigned* pb=(volatile unsigned*)&ldsB4[w][eidx][q];
      pa[0]=wa.x; pa[1]=wa.y; pa[2]=wa.z; pa[3]=wa.w;
      pb[0]=wb.x; pb[1]=wb.y; pb[2]=wb.z; pb[3]=wb.w;
      unsigned long long bal1=__ballot(q==0 && (kk&1));
      unsigned long long bal2=__ballot(q==0 && (kk&2));
      c1t+=__popcll(bal1); c2t+=__popcll(bal2);
      // consume: lane = dim
      if(n==16){
        #pragma unroll
        for(int ee=0; ee<16; ee++){
          fp8 ha, hb;
          ha.__x=lA[ee*64+lane];
          hb.__x=lB[ee*64+lane];
          float fa=(float)ha, fb=(float)hb;
          ap+=fa; an+=fb;
          a1 += ((bal1>>(ee*4))&1) ? fa : 0.f;
          a2 += ((bal2>>(ee*4))&1) ? fa : 0.f;
        }
      } else {
        for(int ee=0; ee<n; ee++){
          fp8 ha, hb;
          ha.__x=lA[ee*64+lane];
          hb.__x=lB[ee*64+lane];
          float fa=(float)ha, fb=(float)hb;
          ap+=fa; an+=fb;
          a1 += ((bal1>>(ee*4))&1) ? fa : 0.f;
          a2 += ((bal2>>(ee*4))&1) ? fa : 0.f;
        }
      }
    }
    float invd=1.f/(float)deg;              // deg >= 1 (self-loops)
    float p =fmaxf(ap*invd, 0.f);
    float qq=fmaxf(an*invd, 0.f);
    P[(size_t)v*64+lane]=__float2half(p);
    Q[(size_t)v*64+lane]=__float2half(qq);
    if(kv&1) acc1+=fmaxf(a1/(float)max(c1t,1), 0.f);
    if(kv&2) acc2+=fmaxf(a2/(float)max(c2t,1), 0.f);
  }
  sh1[w][lane]=acc1; sh2[w][lane]=acc2;
  __syncthreads();
  if(w==0){
    sp1[blockIdx.x*64+lane]=sh1[0][lane]+sh1[1][lane]+sh1[2][lane]+sh1[3][lane];
    sp2[blockIdx.x*64+lane]=sh2[0][lane]+sh2[1][lane]+sh2[2][lane]+sh2[3][lane];
  }
}

// stage 1: 128 blocks, block b reduces rows [b*rows, (b+1)*rows) of sp1/sp2
__global__ void k_reduce_s1(const float* __restrict__ sp1, const float* __restrict__ sp2,
                            int nb, int rows, float* __restrict__ sp1b, float* __restrict__ sp2b){
  __shared__ float s[BS];
  int t=threadIdx.x, lane=t&63, p=t>>6;
  int base=blockIdx.x*rows;
  float a=0.f;
  for(int r=p; r<rows; r+=4){
    int row=base+r;
    if(row<nb) a+=sp1[row*64+lane];
  }
  s[t]=a; __syncthreads();
  if(t<64) sp1b[blockIdx.x*64+t]=s[t]+s[t+64]+s[t+128]+s[t+192];
  __syncthreads();
  a=0.f;
  for(int r=p; r<rows; r+=4){
    int row=base+r;
    if(row<nb) a+=sp2[row*64+lane];
  }
  s[t]=a; __syncthreads();
  if(t<64) sp2b[blockIdx.x*64+t]=s[t]+s[t+64]+s[t+128]+s[t+192];
}

// stage 2: single block over nb2 (=128) rows
__global__ void k_reduce_s2(const float* __restrict__ sp1b, const float* __restrict__ sp2b,
                            int nb2, float* __restrict__ cf){
  __shared__ float s[BS];
  int t=threadIdx.x, lane=t&63, p=t>>6;
  float a=0.f;
  for(int b=p;b<nb2;b+=4) a+=sp1b[b*64+lane];
  s[t]=a; __syncthreads();
  if(t<64) cf[C_SUM1+t]=s[t]+s[t+64]+s[t+128]+s[t+192];
  __syncthreads();
  a=0.f;
  for(int b=p;b<nb2;b+=4) a+=sp2b[b*64+lane];
  s[t]=a; __syncthreads();
  if(t<64) cf[C_SUM2+t]=s[t]+s[t+64]+s[t+128]+s[t+192];
}

__global__ void k_sumv(const float* __restrict__ Wd, float* __restrict__ cf,
                       int sumoff, int voff, float invk){
  __shared__ float s[64];
  int t=threadIdx.x;
  if(t<64){
    float x=cf[sumoff+t]*invk;
    s[t]=1.f/(1.f+expf(-x));
  }
  __syncthreads();
  if(t<64){
    float a=0.f;
    #pragma unroll
    for(int d=0;d<64;d++) a+=Wd[t*64+d]*s[d];
    cf[voff+t]=a;
  }
}

// ---------------- streaming BCE loss over materialized P/Q (thread per node) ----------------
__global__ void k_loss2(const __half* __restrict__ P, const __half* __restrict__ Q,
                        float* __restrict__ cf, int N){
  __shared__ float sv1[64], sv2[64];
  __shared__ float sred[BS];
  int t=threadIdx.x;
  if(t<64){ sv1[t]=cf[C_V1+t]; sv2[t]=cf[C_V2+t]; }
  __syncthreads();
  int i=blockIdx.x*BS+t, st=gridDim.x*BS;
  float acc=0.f;
  for(int v=i; v<N; v+=st){
    const uint4* pr=(const uint4*)(P+(size_t)v*64);
    const uint4* qr=(const uint4*)(Q+(size_t)v*64);
    float a1=0.f,a2=0.f,b1=0.f,b2=0.f;
    #pragma unroll
    for(int c=0;c<8;c++){
      uint4 pu=pr[c], qu=qr[c];
      unsigned arr[4]={pu.x,pu.y,pu.z,pu.w};
      unsigned brr[4]={qu.x,qu.y,qu.z,qu.w};
      #pragma unroll
      for(int j=0;j<4;j++){
        int d=c*8+j*2;
        __half2 ph=*(const __half2*)&arr[j];
        __half2 qh=*(const __half2*)&brr[j];
        float2 pf=__half22float2(ph);
        float2 qf=__half22float2(qh);
        a1=fmaf(pf.x,sv1[d],a1); a1=fmaf(pf.y,sv1[d+1],a1);
        a2=fmaf(pf.x,sv2[d],a2); a2=fmaf(pf.y,sv2[d+1],a2);
        b1=fmaf(qf.x,sv1[d],b1); b1=fmaf(qf.y,sv1[d+1],b1);
        b2=fmaf(qf.x,sv2[d],b2); b2=fmaf(qf.y,sv2[d+1],b2);
      }
    }
    acc += softplusf(-a1)+softplusf(b1)+softplusf(-a2)+softplusf(b2);
  }
  sred[t]=acc;
  __syncthreads();
  for(int o=BS/2;o>0;o>>=1){ if(t<o) sred[t]+=sred[t+o]; __syncthreads(); }
  if(t==0) atomicAdd(&cf[C_LOSS], sred[0]);
}

__global__ void k_final(const float* __restrict__ cf, float* __restrict__ out, int N){
  if(blockIdx.x||threadIdx.x) return;
  out[0]=cf[C_LOSS]/(float)N;
}

extern "C" void kernel_launch(void* const* d_in, const int* in_sizes, int n_in,
                              void* d_out, int out_size, void* d_ws, size_t ws_size,
                              hipStream_t stream) {
  const float* feat    = (const float*)d_in[0];
  const float* Wenc    = (const float*)d_in[1];
  const float* Wdisc   = (const float*)d_in[2];
  const int*   src     = (const int*)d_in[3];
  const int*   dst     = (const int*)d_in[4];
  const int*   permneg = (const int*)d_in[5];
  const int*   perm1   = (const int*)d_in[6];
  const int*   perm2   = (const int*)d_in[7];
  float* out = (float*)d_out;

  int N = in_sizes[5];
  int E = in_sizes[3];
  int target = (int)((double)N*0.8);
  int NB = (N+BS-1)/BS;
  int WORDS = (N+31)/32;
  int gE = (E+BS-1)/BS; if(gE>4096) gE=4096;
  const int SUBB = 2048;
  const int R1B = 128, R1ROWS = SUBB/R1B;
  const int FB = 256, FINB = 128;

  // workspace carve (256B-aligned chunks)
  char* w = (char*)d_ws;
  auto alloc = [&](size_t bytes)->void*{
    void* p = (void*)w;
    w += (bytes + 255) & ~(size_t)255;
    return p;
  };
  int*      ctrl    = (int*)     alloc(4096);
  int*      cntD    = (int*)     alloc((size_t)N*4);
  int*      cntS    = (int*)     alloc((size_t)N*4);
  int*      rowptrD = (int*)     alloc((size_t)(N+1)*4);
  int*      rowptrS = (int*)     alloc((size_t)(N+1)*4);
  int*      curD    = (int*)     alloc((size_t)N*4);
  int*      curS    = (int*)     alloc((size_t)N*4);
  int*      colD    = (int*)     alloc((size_t)E*4);
  int*      colS    = (int*)     alloc((size_t)E*4);
  int*      hop     = (int*)     alloc((size_t)N*4);
  int*      keepPk  = (int*)     alloc((size_t)N*4);
  unsigned* bits    = (unsigned*)alloc((size_t)WORDS*4);
  int*      wordpref= (int*)     alloc((size_t)(WORDS+1)*4);
  int*      fr0     = (int*)     alloc((size_t)N*4);
  int*      fr1     = (int*)     alloc((size_t)N*4);
  int*      part    = (int*)     alloc((size_t)(NB+2)*4);
  int*      hist    = (int*)     alloc(64*4);
  fp8*      FW      = (fp8*)     alloc((size_t)N*64);
  fp8*      FWn     = (fp8*)     alloc((size_t)N*64);
  __half*   P       = (__half*)  alloc((size_t)N*64*2);
  __half*   Q       = (__half*)  alloc((size_t)N*64*2);
  float*    sp1     = (float*)   alloc((size_t)SUBB*64*4);
  float*    sp2     = (float*)   alloc((size_t)SUBB*64*4);
  float*    sp1b    = (float*)   alloc((size_t)R1B*64*4);
  float*    sp2b    = (float*)   alloc((size_t)R1B*64*4);
  float*    cf = (float*)ctrl;

  // --- build both CSRs ---
  k_zero2     <<<NB, BS, 0, stream>>>(cntD, cntS, N);
  k_deg2      <<<gE, BS, 0, stream>>>(src, dst, E, cntS, cntD);
  k_blocksum  <<<NB, BS, 0, stream>>>(cntD, N, part);
  k_scan_block<<<1,  BS, 0, stream>>>(part, NB);
  k_rowptr    <<<NB, BS, 0, stream>>>(cntD, part, N, NB, rowptrD, curD);
  k_blocksum  <<<NB, BS, 0, stream>>>(cntS, N, part);
  k_scan_block<<<1,  BS, 0, stream>>>(part, NB);
  k_rowptr    <<<NB, BS, 0, stream>>>(cntS, part, N, NB, rowptrS, curS);
  k_scatter2  <<<gE, BS, 0, stream>>>(src, dst, E, curD, colD, curS, colS);

  // --- FW = feat @ W_enc (fp8), FWn = FW[perm_neg] ---
  k_fw      <<<2048, BS, 0, stream>>>(feat, Wenc, FW, N);
  k_permrows<<<4096, BS, 0, stream>>>((const unsigned*)FW, permneg, (unsigned*)FWn, N);

  const int* perms[2] = {perm1, perm2};
  for(int pi=0; pi<2; pi++){
    const int* perm = perms[pi];
    k_bfs_init<<<NB, BS, 0, stream>>>(hop, N, perm, ctrl, hist, fr0);
    for(int it=0; it<MAXIT; it++){
      int* frCur = (it&1)? fr1 : fr0;
      int* frNext= (it&1)? fr0 : fr1;
      k_frontier<<<FB,   BS, 0, stream>>>(rowptrS, colS, hop, frCur, frNext, ctrl, it, N);
      k_fin     <<<FINB, BS, 0, stream>>>(hop, perm, frNext, ctrl, N, target, it);
    }
    k_hop_hist  <<<512, BS, 0, stream>>>(hop, N, hist);
    k_cutoff    <<<1, 1, 0, stream>>>(hist, ctrl, target);
    k_zero1     <<<16, BS, 0, stream>>>((int*)bits, WORDS);
    k_flagbits  <<<NB, BS, 0, stream>>>(hop, perm, bits, N, ctrl);
    k_scan_words<<<1,  BS, 0, stream>>>(bits, WORDS, wordpref);
    k_keep      <<<NB, BS, 0, stream>>>(hop, perm, bits, wordpref, keepPk, N, ctrl, pi);
  }

  // --- fused gather: pos/neg rows + both subgraph summaries in one CSR pass ---
  k_mega     <<<SUBB, BS, 0, stream>>>(rowptrD, colD, (const unsigned char*)FW,
                                       (const unsigned char*)FWn, keepPk, P, Q, sp1, sp2, N);
  k_reduce_s1<<<R1B, BS, 0, stream>>>(sp1, sp2, SUBB, R1ROWS, sp1b, sp2b);
  k_reduce_s2<<<1,   BS, 0, stream>>>(sp1b, sp2b, R1B, cf);
  k_sumv     <<<1, 64, 0, stream>>>(Wdisc, cf, C_SUM1, C_V1, 1.f/(float)target);
  k_sumv     <<<1, 64, 0, stream>>>(Wdisc, cf, C_SUM2, C_V2, 1.f/(float)target);

  // --- streaming loss ---
  k_loss2<<<NB, BS, 0, stream>>>(P, Q, cf, N);
  k_final<<<1, 1, 0, stream>>>(cf, out, N);
}